// Round 5
// baseline (230.318 us; speedup 1.0000x reference)
//
#include <hip/hip_runtime.h>
#include <hip/hip_cooperative_groups.h>
#include <math.h>

namespace cg = cooperative_groups;

#define DCH 256      // d_model
#define BSZ 512      // graphs
#define NPG 200      // nodes per graph
#define G4  1024     // 4*D
#define K2  512      // 2*D
#define KSD 8        // discrete-path k-split (gates GEMM)
#define KSM 2        // mega-path k-split (gates GEMM)

__device__ __forceinline__ float sigf(float x) { return 1.0f / (1.0f + __expf(-x)); }

// ---------------------------------------------------------------------------
// Shared LSTM-cell + online-softmax attention phase; 256 logical threads.
// smem layout (4384 floats): qs[256] | red_r[16][256] | red_m[16] | red_s[16]
// ---------------------------------------------------------------------------
template<int KS>
__device__ __forceinline__ void attn_phase(
    float* smem, int b, int t,
    const float* __restrict__ gpart, const float* __restrict__ b_ih,
    const float* __restrict__ b_hh, const float* __restrict__ node,
    const int* __restrict__ node_num, float* __restrict__ cbuf,
    float* __restrict__ hr, int first)
{
    float* qs = smem;
    float (*red_r)[DCH] = (float (*)[DCH])(smem + 256);
    float* red_m = smem + 4352;
    float* red_s = smem + 4368;

    // ---- LSTM cell (torch gate order i,f,g,o) ----
    float gv[4];
    #pragma unroll
    for (int q = 0; q < 4; ++q) {
        const int idx = q * DCH + t;
        float v = b_ih[idx] + b_hh[idx];
        if (!first) {
            #pragma unroll
            for (int z = 0; z < KS; ++z)
                v += gpart[(size_t)z * BSZ * G4 + (size_t)b * G4 + idx];
        }
        gv[q] = v;
    }
    const float c_old = first ? 0.0f : cbuf[b * DCH + t];
    const float cn = sigf(gv[1]) * c_old + sigf(gv[0]) * tanhf(gv[2]);
    const float hn = sigf(gv[3]) * tanhf(cn);
    cbuf[b * DCH + t] = cn;
    hr[(size_t)b * K2 + t] = hn;
    qs[t] = hn;
    __syncthreads();

    // ---- attention: 16-lane clusters, 2 nodes/cluster/iter, prefetch ----
    const int w = t >> 6, l = t & 63;
    const int p = l & 15;
    const int g = w * 4 + (l >> 4);
    const int cnt = node_num[b];
    const float* nb = node + (size_t)b * NPG * DCH;

    float4 qv[4];
    #pragma unroll
    for (int j = 0; j < 4; ++j) qv[j] = *(const float4*)(qs + j * 64 + p * 4);

    float m = -INFINITY, s = 0.0f;
    float4 racc[4] = {};
    const int nit = (cnt + 31) >> 5;

    float4 x0[4], x1[4];
    {
        const int n0 = 2 * g;
        #pragma unroll
        for (int j = 0; j < 4; ++j) {
            x0[j] = (n0     < cnt) ? *(const float4*)(nb + (size_t)n0 * DCH + j * 64 + p * 4)
                                   : make_float4(0.f, 0.f, 0.f, 0.f);
            x1[j] = (n0 + 1 < cnt) ? *(const float4*)(nb + (size_t)(n0 + 1) * DCH + j * 64 + p * 4)
                                   : make_float4(0.f, 0.f, 0.f, 0.f);
        }
    }

    for (int it = 0; it < nit; ++it) {
        float4 y0[4], y1[4];
        const int np = (it + 1) * 32 + 2 * g;
        #pragma unroll
        for (int j = 0; j < 4; ++j) {
            y0[j] = (np     < cnt) ? *(const float4*)(nb + (size_t)np * DCH + j * 64 + p * 4)
                                   : make_float4(0.f, 0.f, 0.f, 0.f);
            y1[j] = (np + 1 < cnt) ? *(const float4*)(nb + (size_t)(np + 1) * DCH + j * 64 + p * 4)
                                   : make_float4(0.f, 0.f, 0.f, 0.f);
        }
        float e0 = 0.f, e1 = 0.f;
        #pragma unroll
        for (int j = 0; j < 4; ++j) {
            e0 += x0[j].x * qv[j].x + x0[j].y * qv[j].y + x0[j].z * qv[j].z + x0[j].w * qv[j].w;
            e1 += x1[j].x * qv[j].x + x1[j].y * qv[j].y + x1[j].z * qv[j].z + x1[j].w * qv[j].w;
        }
        #pragma unroll
        for (int off = 1; off < 16; off <<= 1) {
            e0 += __shfl_xor(e0, off);
            e1 += __shfl_xor(e1, off);
        }
        const int n0 = it * 32 + 2 * g;
        if (n0     >= cnt) e0 = -INFINITY;
        if (n0 + 1 >= cnt) e1 = -INFINITY;
        const float mn = fmaxf(m, fmaxf(e0, e1));
        if (mn > -INFINITY) {
            const float sc = __expf(m - mn);
            const float w0 = __expf(e0 - mn);
            const float w1 = __expf(e1 - mn);
            s = s * sc + w0 + w1;
            #pragma unroll
            for (int j = 0; j < 4; ++j) {
                racc[j].x = racc[j].x * sc + w0 * x0[j].x + w1 * x1[j].x;
                racc[j].y = racc[j].y * sc + w0 * x0[j].y + w1 * x1[j].y;
                racc[j].z = racc[j].z * sc + w0 * x0[j].z + w1 * x1[j].z;
                racc[j].w = racc[j].w * sc + w0 * x0[j].w + w1 * x1[j].w;
            }
            m = mn;
        }
        #pragma unroll
        for (int j = 0; j < 4; ++j) { x0[j] = y0[j]; x1[j] = y1[j]; }
    }

    #pragma unroll
    for (int j = 0; j < 4; ++j)
        *(float4*)(&red_r[g][j * 64 + p * 4]) = racc[j];
    if (p == 0) { red_m[g] = m; red_s[g] = s; }
    __syncthreads();

    float M = -INFINITY;
    #pragma unroll
    for (int g2 = 0; g2 < 16; ++g2) M = fmaxf(M, red_m[g2]);
    float stot = 0.0f, rtot = 0.0f;
    #pragma unroll
    for (int g2 = 0; g2 < 16; ++g2) {
        const float sc = __expf(red_m[g2] - M);
        stot += sc * red_s[g2];
        rtot += sc * red_r[g2][t];
    }
    hr[(size_t)b * K2 + DCH + t] = rtot / (stot + 1e-6f);
    __syncthreads();   // protect smem before next phase reuses it
}

// ---------------------------------------------------------------------------
// 512-thread GEMM phase for mega kernel: 64x64 tile, 2x4 micro, BK=32.
// smem: As [32][68] | Bs [32][68] (4352 floats of the caller's buffer).
// ---------------------------------------------------------------------------
__device__ __forceinline__ void gemm_phase512(
    float* smem, int tid, int bx, int by, int bz, int Kper,
    const float* __restrict__ A, const float* __restrict__ Bm,
    const float* __restrict__ Whh, const float* __restrict__ bias,
    float* __restrict__ Cp, int N)
{
    float (*As)[68] = (float (*)[68])smem;
    float (*Bs)[68] = (float (*)[68])(smem + 2176);
    const int bm = by * 64, bn = bx * 64, kbase = bz * Kper;
    const int tx = tid & 15, ty = tid >> 4;        // 16 x 32
    float acc[2][4] = {};

    for (int k0 = 0; k0 < Kper; k0 += 32) {
        const int kg = kbase + k0;                 // block-uniform
        const bool addhh = (Whh != nullptr) && (kg < DCH);
        {
            const int r = tid >> 3, cc = tid & 7;  // 512 float4 = 64 rows x 8
            const float4 v = *(const float4*)(A + (size_t)(bm + r) * K2 + kg + 4 * cc);
            As[4*cc+0][r] = v.x; As[4*cc+1][r] = v.y; As[4*cc+2][r] = v.z; As[4*cc+3][r] = v.w;
            float4 u = *(const float4*)(Bm + (size_t)(bn + r) * K2 + kg + 4 * cc);
            if (addhh) {
                const float4 h4 = *(const float4*)(Whh + (size_t)(bn + r) * DCH + kg + 4 * cc);
                u.x += h4.x; u.y += h4.y; u.z += h4.z; u.w += h4.w;
            }
            Bs[4*cc+0][r] = u.x; Bs[4*cc+1][r] = u.y; Bs[4*cc+2][r] = u.z; Bs[4*cc+3][r] = u.w;
        }
        __syncthreads();
        #pragma unroll
        for (int kk = 0; kk < 32; ++kk) {
            const float2 a2 = *(const float2*)(&As[kk][2 * ty]);
            const float4 b4 = *(const float4*)(&Bs[kk][4 * tx]);
            acc[0][0] += a2.x * b4.x; acc[0][1] += a2.x * b4.y; acc[0][2] += a2.x * b4.z; acc[0][3] += a2.x * b4.w;
            acc[1][0] += a2.y * b4.x; acc[1][1] += a2.y * b4.y; acc[1][2] += a2.y * b4.z; acc[1][3] += a2.y * b4.w;
        }
        __syncthreads();
    }

    float4 bv = make_float4(0.f, 0.f, 0.f, 0.f);
    if (bias) bv = *(const float4*)(bias + bn + 4 * tx);
    #pragma unroll
    for (int i = 0; i < 2; ++i) {
        float4 o;
        o.x = acc[i][0] + bv.x; o.y = acc[i][1] + bv.y;
        o.z = acc[i][2] + bv.z; o.w = acc[i][3] + bv.w;
        *(float4*)(Cp + (size_t)(bm + 2 * ty + i) * N + bn + 4 * tx) = o;
    }
}

// ---------------------------------------------------------------------------
// Mega-kernel v2: 256 blocks x 512 threads (fits coop co-residency limit).
// Each block's two 256-thread halves run graphs 2*bid and 2*bid+1 in attn
// phases; all 512 threads cooperate in GEMM phases. 7 grid syncs.
// ---------------------------------------------------------------------------
__global__ void __launch_bounds__(512, 2) mega2_kernel(
    const float* __restrict__ node, const int* __restrict__ node_num,
    const float* __restrict__ W_ih, const float* __restrict__ W_hh,
    const float* __restrict__ b_ih, const float* __restrict__ b_hh,
    const float* __restrict__ Wo,   const float* __restrict__ bo,
    float* __restrict__ out, float* __restrict__ cbuf, float* __restrict__ hr,
    float* __restrict__ gpart)
{
    cg::grid_group grid = cg::this_grid();
    __shared__ __align__(16) float smem[2][4384];
    const int bid = blockIdx.x;          // 0..255
    const int tid = threadIdx.x;         // 0..511
    const int half = tid >> 8, t = tid & 255;
    const int b = bid * 2 + half;

    attn_phase<KSM>(smem[half], b, t, gpart, b_ih, b_hh, node, node_num, cbuf, hr, 1);
    __threadfence(); grid.sync(); __threadfence();

    for (int s = 1; s < 4; ++s) {
        {   // gates GEMM: M=512,N=1024,K=512 ; tasks 16x8x2, Kper=256
            const int bx = bid & 15, by = (bid >> 4) & 7, bz = bid >> 7;
            gemm_phase512(smem[0], tid, bx, by, bz, K2 / KSM, hr, W_ih, W_hh,
                          nullptr, gpart + (size_t)bz * BSZ * G4, G4);
        }
        __threadfence(); grid.sync(); __threadfence();
        attn_phase<KSM>(smem[half], b, t, gpart, b_ih, b_hh, node, node_num, cbuf, hr, 0);
        __threadfence(); grid.sync(); __threadfence();
    }

    // out GEMM: M=512,N=256,K=512, no k-split, bias fused; 32 blocks
    if (bid < 32) {
        const int bx = bid & 3, by = bid >> 2;
        gemm_phase512(smem[0], tid, bx, by, 0, K2, hr, Wo, nullptr, bo, out, DCH);
    }
}

// ---------------------------------------------------------------------------
// Discrete-path kernels (round-3 known-good structure)
// ---------------------------------------------------------------------------
template<int BM, int BN, int BK>
__global__ __launch_bounds__(256) void gemm_nt_part(
    const float* __restrict__ A, const float* __restrict__ Bm,
    const float* __restrict__ Whh, const float* __restrict__ bias,
    float* __restrict__ Cpart, int M, int N, int K, int Kper)
{
    constexpr int PAD = 4;
    __shared__ __align__(16) float As[BK][BM + PAD];
    __shared__ __align__(16) float Bs[BK][BN + PAD];
    const int tid = threadIdx.x;
    const int bm = blockIdx.y * BM, bn = blockIdx.x * BN;
    const int kbase = blockIdx.z * Kper;
    const int tx = tid & 15, ty = tid >> 4;
    float acc[4][4] = {};

    for (int k0 = 0; k0 < Kper; k0 += BK) {
        const int kg = kbase + k0;
        const bool addhh = (Whh != nullptr) && (kg < DCH);
        #pragma unroll
        for (int i = 0; i < (BM * BK) / (256 * 4); ++i) {
            const int id = tid + i * 256;
            const int r = id >> 3, cc = id & 7;
            const float4 v = *(const float4*)(A + (size_t)(bm + r) * K + kg + 4 * cc);
            As[4*cc+0][r] = v.x; As[4*cc+1][r] = v.y; As[4*cc+2][r] = v.z; As[4*cc+3][r] = v.w;
            float4 u = *(const float4*)(Bm + (size_t)(bn + r) * K + kg + 4 * cc);
            if (addhh) {
                const float4 h4 = *(const float4*)(Whh + (size_t)(bn + r) * DCH + kg + 4 * cc);
                u.x += h4.x; u.y += h4.y; u.z += h4.z; u.w += h4.w;
            }
            Bs[4*cc+0][r] = u.x; Bs[4*cc+1][r] = u.y; Bs[4*cc+2][r] = u.z; Bs[4*cc+3][r] = u.w;
        }
        __syncthreads();
        #pragma unroll
        for (int kk = 0; kk < BK; ++kk) {
            const float4 a4 = *(const float4*)(&As[kk][4 * ty]);
            const float4 b4 = *(const float4*)(&Bs[kk][4 * tx]);
            acc[0][0] += a4.x * b4.x; acc[0][1] += a4.x * b4.y; acc[0][2] += a4.x * b4.z; acc[0][3] += a4.x * b4.w;
            acc[1][0] += a4.y * b4.x; acc[1][1] += a4.y * b4.y; acc[1][2] += a4.y * b4.z; acc[1][3] += a4.y * b4.w;
            acc[2][0] += a4.z * b4.x; acc[2][1] += a4.z * b4.y; acc[2][2] += a4.z * b4.z; acc[2][3] += a4.z * b4.w;
            acc[3][0] += a4.w * b4.x; acc[3][1] += a4.w * b4.y; acc[3][2] += a4.w * b4.z; acc[3][3] += a4.w * b4.w;
        }
        __syncthreads();
    }

    float4 bv = make_float4(0.f, 0.f, 0.f, 0.f);
    if (bias) bv = *(const float4*)(bias + bn + 4 * tx);
    float* Cp = Cpart + (size_t)blockIdx.z * M * N;
    #pragma unroll
    for (int i = 0; i < 4; ++i) {
        float4 o;
        o.x = acc[i][0] + bv.x; o.y = acc[i][1] + bv.y;
        o.z = acc[i][2] + bv.z; o.w = acc[i][3] + bv.w;
        *(float4*)(Cp + (size_t)(bm + 4 * ty + i) * N + bn + 4 * tx) = o;
    }
}

__global__ __launch_bounds__(256) void lstm_attn_kernel(
    const float* __restrict__ gpart,
    const float* __restrict__ b_ih, const float* __restrict__ b_hh,
    const float* __restrict__ node, const int* __restrict__ node_num,
    float* __restrict__ cbuf, float* __restrict__ hr, int first)
{
    __shared__ __align__(16) float smem[4384];
    attn_phase<KSD>(smem, blockIdx.x, threadIdx.x, gpart, b_ih, b_hh,
                    node, node_num, cbuf, hr, first);
}

// Diagnostic: ~70us spin so it shows in rocprof top-5; Workgroup_Size
// encodes the coop-launch failure cause (65 / 130 / 192+err).
__global__ void diag_spin_kernel() {
    const long long start = wall_clock64();
    while (wall_clock64() - start < 7000LL) { }   // 7000 ticks @100MHz = 70us
}

// ---------------------------------------------------------------------------
extern "C" void kernel_launch(void* const* d_in, const int* in_sizes, int n_in,
                              void* d_out, int out_size, void* d_ws, size_t ws_size,
                              hipStream_t stream)
{
    const float* node     = (const float*)d_in[0];
    const int*   node_num = (const int*)  d_in[1];
    const float* W_ih     = (const float*)d_in[2];
    const float* W_hh     = (const float*)d_in[3];
    const float* b_ih     = (const float*)d_in[4];
    const float* b_hh     = (const float*)d_in[5];
    const float* Wo       = (const float*)d_in[6];
    const float* bo       = (const float*)d_in[7];
    float* out = (float*)d_out;

    float* ws    = (float*)d_ws;
    float* cbuf  = ws;                        // 512*256
    float* hr    = cbuf + BSZ * DCH;          // 512*512
    float* gpart = hr + BSZ * K2;             // KSD*512*1024 (16 MB, mega uses 2 slices)

    int dev = 0;
    (void)hipGetDevice(&dev);
    int coopAttr = 0;
    (void)hipDeviceGetAttribute(&coopAttr, hipDeviceAttributeCooperativeLaunch, dev);
    int ncu = 0;
    (void)hipDeviceGetAttribute(&ncu, hipDeviceAttributeMultiprocessorCount, dev);
    int mb = 0;
    (void)hipOccupancyMaxActiveBlocksPerMultiprocessor(&mb, mega2_kernel, 512, 0);

    const bool ok = (coopAttr != 0) && (mb * ncu >= 256);
    hipError_t lerr = hipSuccess;
    if (ok) {
        void* args[] = {
            (void*)&node, (void*)&node_num, (void*)&W_ih, (void*)&W_hh,
            (void*)&b_ih, (void*)&b_hh, (void*)&Wo, (void*)&bo,
            (void*)&out, (void*)&cbuf, (void*)&hr, (void*)&gpart
        };
        lerr = hipLaunchCooperativeKernel((void*)mega2_kernel, dim3(256), dim3(512),
                                          args, 0, stream);
        if (lerr != hipSuccess) (void)hipGetLastError();   // clear sticky error
    }

    if (!ok || lerr != hipSuccess) {
        const int code = (!coopAttr) ? 65
                       : (mb * ncu < 256) ? 130
                       : 192 + (((int)lerr) & 63);
        diag_spin_kernel<<<1, code, 0, stream>>>();

        // --- discrete fallback (round-3 structure, 8 dispatches) ---
        lstm_attn_kernel<<<BSZ, 256, 0, stream>>>(gpart, b_ih, b_hh, node, node_num, cbuf, hr, 1);
        for (int s = 1; s < 4; ++s) {
            gemm_nt_part<64, 64, 32><<<dim3(G4 / 64, BSZ / 64, KSD), 256, 0, stream>>>(
                hr, W_ih, W_hh, nullptr, gpart, BSZ, G4, K2, K2 / KSD);
            lstm_attn_kernel<<<BSZ, 256, 0, stream>>>(gpart, b_ih, b_hh, node, node_num, cbuf, hr, 0);
        }
        // out GEMM: no k-split, bias fused -> writes d_out directly
        gemm_nt_part<64, 64, 32><<<dim3(DCH / 64, BSZ / 64, 1), 256, 0, stream>>>(
            hr, Wo, nullptr, bo, out, BSZ, DCH, K2, K2);
    }
}

// Round 6
// 228.923 us; speedup vs baseline: 1.0061x; 1.0061x over previous
//
#include <hip/hip_runtime.h>
#include <hip/hip_cooperative_groups.h>
#include <math.h>

namespace cg = cooperative_groups;

#define DCH 256      // d_model
#define BSZ 512      // graphs
#define NPG 200      // nodes per graph
#define G4  1024     // 4*D
#define K2  512      // 2*D
#define KSD 8        // discrete-path k-split (gates GEMM)
#define KSM 4        // mega-path k-split (gates GEMM): 16x8x4 = 512 sub-tasks

__device__ __forceinline__ float sigf(float x) { return 1.0f / (1.0f + __expf(-x)); }

// ---------------------------------------------------------------------------
// Shared LSTM-cell + online-softmax attention phase; 256 logical threads.
// smem layout (4384 floats): qs[256] | red_r[16][256] | red_m[16] | red_s[16]
// ---------------------------------------------------------------------------
template<int KS>
__device__ __forceinline__ void attn_phase(
    float* smem, int b, int t,
    const float* __restrict__ gpart, const float* __restrict__ b_ih,
    const float* __restrict__ b_hh, const float* __restrict__ node,
    const int* __restrict__ node_num, float* __restrict__ cbuf,
    float* __restrict__ hr, int first)
{
    float* qs = smem;
    float (*red_r)[DCH] = (float (*)[DCH])(smem + 256);
    float* red_m = smem + 4352;
    float* red_s = smem + 4368;

    // ---- LSTM cell (torch gate order i,f,g,o) ----
    float gv[4];
    #pragma unroll
    for (int q = 0; q < 4; ++q) {
        const int idx = q * DCH + t;
        float v = b_ih[idx] + b_hh[idx];
        if (!first) {
            #pragma unroll
            for (int z = 0; z < KS; ++z)
                v += gpart[(size_t)z * BSZ * G4 + (size_t)b * G4 + idx];
        }
        gv[q] = v;
    }
    const float c_old = first ? 0.0f : cbuf[b * DCH + t];
    const float cn = sigf(gv[1]) * c_old + sigf(gv[0]) * tanhf(gv[2]);
    const float hn = sigf(gv[3]) * tanhf(cn);
    cbuf[b * DCH + t] = cn;
    hr[(size_t)b * K2 + t] = hn;
    qs[t] = hn;
    __syncthreads();

    // ---- attention: 16-lane clusters, 2 nodes/cluster/iter, prefetch ----
    const int w = t >> 6, l = t & 63;
    const int p = l & 15;
    const int g = w * 4 + (l >> 4);
    const int cnt = node_num[b];
    const float* nb = node + (size_t)b * NPG * DCH;

    float4 qv[4];
    #pragma unroll
    for (int j = 0; j < 4; ++j) qv[j] = *(const float4*)(qs + j * 64 + p * 4);

    float m = -INFINITY, s = 0.0f;
    float4 racc[4] = {};
    const int nit = (cnt + 31) >> 5;

    float4 x0[4], x1[4];
    {
        const int n0 = 2 * g;
        #pragma unroll
        for (int j = 0; j < 4; ++j) {
            x0[j] = (n0     < cnt) ? *(const float4*)(nb + (size_t)n0 * DCH + j * 64 + p * 4)
                                   : make_float4(0.f, 0.f, 0.f, 0.f);
            x1[j] = (n0 + 1 < cnt) ? *(const float4*)(nb + (size_t)(n0 + 1) * DCH + j * 64 + p * 4)
                                   : make_float4(0.f, 0.f, 0.f, 0.f);
        }
    }

    for (int it = 0; it < nit; ++it) {
        float4 y0[4], y1[4];
        const int np = (it + 1) * 32 + 2 * g;
        #pragma unroll
        for (int j = 0; j < 4; ++j) {
            y0[j] = (np     < cnt) ? *(const float4*)(nb + (size_t)np * DCH + j * 64 + p * 4)
                                   : make_float4(0.f, 0.f, 0.f, 0.f);
            y1[j] = (np + 1 < cnt) ? *(const float4*)(nb + (size_t)(np + 1) * DCH + j * 64 + p * 4)
                                   : make_float4(0.f, 0.f, 0.f, 0.f);
        }
        float e0 = 0.f, e1 = 0.f;
        #pragma unroll
        for (int j = 0; j < 4; ++j) {
            e0 += x0[j].x * qv[j].x + x0[j].y * qv[j].y + x0[j].z * qv[j].z + x0[j].w * qv[j].w;
            e1 += x1[j].x * qv[j].x + x1[j].y * qv[j].y + x1[j].z * qv[j].z + x1[j].w * qv[j].w;
        }
        #pragma unroll
        for (int off = 1; off < 16; off <<= 1) {
            e0 += __shfl_xor(e0, off);
            e1 += __shfl_xor(e1, off);
        }
        const int n0 = it * 32 + 2 * g;
        if (n0     >= cnt) e0 = -INFINITY;
        if (n0 + 1 >= cnt) e1 = -INFINITY;
        const float mn = fmaxf(m, fmaxf(e0, e1));
        if (mn > -INFINITY) {
            const float sc = __expf(m - mn);
            const float w0 = __expf(e0 - mn);
            const float w1 = __expf(e1 - mn);
            s = s * sc + w0 + w1;
            #pragma unroll
            for (int j = 0; j < 4; ++j) {
                racc[j].x = racc[j].x * sc + w0 * x0[j].x + w1 * x1[j].x;
                racc[j].y = racc[j].y * sc + w0 * x0[j].y + w1 * x1[j].y;
                racc[j].z = racc[j].z * sc + w0 * x0[j].z + w1 * x1[j].z;
                racc[j].w = racc[j].w * sc + w0 * x0[j].w + w1 * x1[j].w;
            }
            m = mn;
        }
        #pragma unroll
        for (int j = 0; j < 4; ++j) { x0[j] = y0[j]; x1[j] = y1[j]; }
    }

    #pragma unroll
    for (int j = 0; j < 4; ++j)
        *(float4*)(&red_r[g][j * 64 + p * 4]) = racc[j];
    if (p == 0) { red_m[g] = m; red_s[g] = s; }
    __syncthreads();

    float M = -INFINITY;
    #pragma unroll
    for (int g2 = 0; g2 < 16; ++g2) M = fmaxf(M, red_m[g2]);
    float stot = 0.0f, rtot = 0.0f;
    #pragma unroll
    for (int g2 = 0; g2 < 16; ++g2) {
        const float sc = __expf(red_m[g2] - M);
        stot += sc * red_s[g2];
        rtot += sc * red_r[g2][t];
    }
    hr[(size_t)b * K2 + DCH + t] = rtot / (stot + 1e-6f);
    __syncthreads();   // protect smem before next phase reuses it
}

// ---------------------------------------------------------------------------
// 256-thread GEMM phase (round-3 proven 4x4 micro): 64x64 tile, BK=32.
// smem: As [32][68] | Bs [32][68] (4352 floats). NOTE: __syncthreads inside
// syncs the full 512-thread block; both halves run identical-trip-count
// phases in lockstep, so barrier counts always match.
// ---------------------------------------------------------------------------
__device__ __forceinline__ void gemm_phase256(
    float* smem, int t, int bx, int by, int kbase, int Kper,
    const float* __restrict__ A, const float* __restrict__ Bm,
    const float* __restrict__ Whh, const float* __restrict__ bias,
    float* __restrict__ Cp, int N)
{
    float (*As)[68] = (float (*)[68])smem;
    float (*Bs)[68] = (float (*)[68])(smem + 2176);
    const int bm = by * 64, bn = bx * 64;
    const int tx = t & 15, ty = t >> 4;
    float acc[4][4] = {};

    for (int k0 = 0; k0 < Kper; k0 += 32) {
        const int kg = kbase + k0;                 // uniform over sub-block
        const bool addhh = (Whh != nullptr) && (kg < DCH);
        #pragma unroll
        for (int i = 0; i < 2; ++i) {
            const int id = t + i * 256;            // float4 id
            const int r = id >> 3, cc = id & 7;
            const float4 v = *(const float4*)(A + (size_t)(bm + r) * K2 + kg + 4 * cc);
            As[4*cc+0][r] = v.x; As[4*cc+1][r] = v.y; As[4*cc+2][r] = v.z; As[4*cc+3][r] = v.w;
            float4 u = *(const float4*)(Bm + (size_t)(bn + r) * K2 + kg + 4 * cc);
            if (addhh) {
                const float4 h4 = *(const float4*)(Whh + (size_t)(bn + r) * DCH + kg + 4 * cc);
                u.x += h4.x; u.y += h4.y; u.z += h4.z; u.w += h4.w;
            }
            Bs[4*cc+0][r] = u.x; Bs[4*cc+1][r] = u.y; Bs[4*cc+2][r] = u.z; Bs[4*cc+3][r] = u.w;
        }
        __syncthreads();
        #pragma unroll
        for (int kk = 0; kk < 32; ++kk) {
            const float4 a4 = *(const float4*)(&As[kk][4 * ty]);
            const float4 b4 = *(const float4*)(&Bs[kk][4 * tx]);
            acc[0][0] += a4.x * b4.x; acc[0][1] += a4.x * b4.y; acc[0][2] += a4.x * b4.z; acc[0][3] += a4.x * b4.w;
            acc[1][0] += a4.y * b4.x; acc[1][1] += a4.y * b4.y; acc[1][2] += a4.y * b4.z; acc[1][3] += a4.y * b4.w;
            acc[2][0] += a4.z * b4.x; acc[2][1] += a4.z * b4.y; acc[2][2] += a4.z * b4.z; acc[2][3] += a4.z * b4.w;
            acc[3][0] += a4.w * b4.x; acc[3][1] += a4.w * b4.y; acc[3][2] += a4.w * b4.z; acc[3][3] += a4.w * b4.w;
        }
        __syncthreads();
    }

    float4 bv = make_float4(0.f, 0.f, 0.f, 0.f);
    if (bias) bv = *(const float4*)(bias + bn + 4 * tx);
    #pragma unroll
    for (int i = 0; i < 4; ++i) {
        float4 o;
        o.x = acc[i][0] + bv.x; o.y = acc[i][1] + bv.y;
        o.z = acc[i][2] + bv.z; o.w = acc[i][3] + bv.w;
        *(float4*)(Cp + (size_t)(bm + 4 * ty + i) * N + bn + 4 * tx) = o;
    }
}

// ---------------------------------------------------------------------------
// Mega-kernel v3: 256 blocks x 512 threads = 512 lockstep 256-thread
// sub-blocks. No manual threadfence (grid.sync provides agent acq-rel).
// ---------------------------------------------------------------------------
__global__ void __launch_bounds__(512, 1) mega3_kernel(
    const float* __restrict__ node, const int* __restrict__ node_num,
    const float* __restrict__ W_ih, const float* __restrict__ W_hh,
    const float* __restrict__ b_ih, const float* __restrict__ b_hh,
    const float* __restrict__ Wo,   const float* __restrict__ bo,
    float* __restrict__ out, float* __restrict__ cbuf, float* __restrict__ hr,
    float* __restrict__ gpart)
{
    cg::grid_group grid = cg::this_grid();
    __shared__ __align__(16) float smem[2][4384];
    const int bid = blockIdx.x;          // 0..255
    const int tid = threadIdx.x;         // 0..511
    const int half = tid >> 8, t = tid & 255;
    const int sub = bid * 2 + half;      // 0..511

    // step 1: gates = biases only
    attn_phase<KSM>(smem[half], sub, t, gpart, b_ih, b_hh, node, node_num, cbuf, hr, 1);
    grid.sync();

    for (int s = 1; s < 4; ++s) {
        {   // gates GEMM: M=512,N=1024,K=512 ; 16x8x4 sub-tasks, Kper=128
            const int bx = sub & 15, by = (sub >> 4) & 7, bz = sub >> 7;
            gemm_phase256(smem[half], t, bx, by, bz * (K2 / KSM), K2 / KSM,
                          hr, W_ih, W_hh, nullptr,
                          gpart + (size_t)bz * BSZ * G4, G4);
        }
        grid.sync();
        attn_phase<KSM>(smem[half], sub, t, gpart, b_ih, b_hh, node, node_num, cbuf, hr, 0);
        grid.sync();
    }

    // out GEMM: M=512,N=256,K=512, full K, bias fused; sub-blocks 0..31
    if (sub < 32) {
        const int bx = sub & 3, by = sub >> 2;
        gemm_phase256(smem[half], t, bx, by, 0, K2, hr, Wo, nullptr, bo, out, DCH);
    }
}

// ---------------------------------------------------------------------------
// Discrete-path fallback kernels (round-3 known-good structure)
// ---------------------------------------------------------------------------
template<int BM, int BN, int BK>
__global__ __launch_bounds__(256) void gemm_nt_part(
    const float* __restrict__ A, const float* __restrict__ Bm,
    const float* __restrict__ Whh, const float* __restrict__ bias,
    float* __restrict__ Cpart, int M, int N, int K, int Kper)
{
    __shared__ __align__(16) float smem[4352];
    gemm_phase256(smem, threadIdx.x, blockIdx.x, blockIdx.y,
                  blockIdx.z * Kper, Kper, A, Bm, Whh, bias,
                  Cpart + (size_t)blockIdx.z * M * N, N);
}

__global__ __launch_bounds__(256) void lstm_attn_kernel(
    const float* __restrict__ gpart,
    const float* __restrict__ b_ih, const float* __restrict__ b_hh,
    const float* __restrict__ node, const int* __restrict__ node_num,
    float* __restrict__ cbuf, float* __restrict__ hr, int first)
{
    __shared__ __align__(16) float smem[4384];
    attn_phase<KSD>(smem, blockIdx.x, threadIdx.x, gpart, b_ih, b_hh,
                    node, node_num, cbuf, hr, first);
}

// Diagnostic: ~70us spin; Workgroup_Size encodes coop-launch failure cause.
__global__ void diag_spin_kernel() {
    const long long start = wall_clock64();
    while (wall_clock64() - start < 7000LL) { }
}

// ---------------------------------------------------------------------------
extern "C" void kernel_launch(void* const* d_in, const int* in_sizes, int n_in,
                              void* d_out, int out_size, void* d_ws, size_t ws_size,
                              hipStream_t stream)
{
    const float* node     = (const float*)d_in[0];
    const int*   node_num = (const int*)  d_in[1];
    const float* W_ih     = (const float*)d_in[2];
    const float* W_hh     = (const float*)d_in[3];
    const float* b_ih     = (const float*)d_in[4];
    const float* b_hh     = (const float*)d_in[5];
    const float* Wo       = (const float*)d_in[6];
    const float* bo       = (const float*)d_in[7];
    float* out = (float*)d_out;

    float* ws    = (float*)d_ws;
    float* cbuf  = ws;                        // 512*256
    float* hr    = cbuf + BSZ * DCH;          // 512*512
    float* gpart = hr + BSZ * K2;             // KSD*512*1024 (16 MB; mega uses 4 slices)

    int dev = 0;
    (void)hipGetDevice(&dev);
    int coopAttr = 0;
    (void)hipDeviceGetAttribute(&coopAttr, hipDeviceAttributeCooperativeLaunch, dev);
    int ncu = 0;
    (void)hipDeviceGetAttribute(&ncu, hipDeviceAttributeMultiprocessorCount, dev);
    int mb = 0;
    (void)hipOccupancyMaxActiveBlocksPerMultiprocessor(&mb, mega3_kernel, 512, 0);

    const bool ok = (coopAttr != 0) && (mb * ncu >= 256);
    hipError_t lerr = hipSuccess;
    if (ok) {
        void* args[] = {
            (void*)&node, (void*)&node_num, (void*)&W_ih, (void*)&W_hh,
            (void*)&b_ih, (void*)&b_hh, (void*)&Wo, (void*)&bo,
            (void*)&out, (void*)&cbuf, (void*)&hr, (void*)&gpart
        };
        lerr = hipLaunchCooperativeKernel((void*)mega3_kernel, dim3(256), dim3(512),
                                          args, 0, stream);
        if (lerr != hipSuccess) (void)hipGetLastError();   // clear sticky error
    }

    if (!ok || lerr != hipSuccess) {
        const int code = (!coopAttr) ? 65
                       : (mb * ncu < 256) ? 130
                       : 192 + (((int)lerr) & 63);
        diag_spin_kernel<<<1, code, 0, stream>>>();

        // --- discrete fallback (round-3 structure, 8 dispatches) ---
        lstm_attn_kernel<<<BSZ, 256, 0, stream>>>(gpart, b_ih, b_hh, node, node_num, cbuf, hr, 1);
        for (int s = 1; s < 4; ++s) {
            gemm_nt_part<64, 64, 32><<<dim3(G4 / 64, BSZ / 64, KSD), 256, 0, stream>>>(
                hr, W_ih, W_hh, nullptr, gpart, BSZ, G4, K2, K2 / KSD);
            lstm_attn_kernel<<<BSZ, 256, 0, stream>>>(gpart, b_ih, b_hh, node, node_num, cbuf, hr, 0);
        }
        gemm_nt_part<64, 64, 32><<<dim3(DCH / 64, BSZ / 64, 1), 256, 0, stream>>>(
            hr, Wo, nullptr, bo, out, BSZ, DCH, K2, K2);
    }
}

// Round 7
// 129.164 us; speedup vs baseline: 1.7831x; 1.7723x over previous
//
#include <hip/hip_runtime.h>
#include <math.h>

#define DCH 256      // d_model
#define BSZ 512      // graphs
#define NPG 200      // nodes per graph
#define G4  1024     // 4*D
#define K2  512      // 2*D
#define KSD 8        // k-split for gates GEMM (grid 16x4x8 = 512 blocks)

__device__ __forceinline__ float sigf(float x) { return 1.0f / (1.0f + __expf(-x)); }

// ---------------------------------------------------------------------------
// Gates GEMM partial: Cpart[z][m,n] = sum_{k in slice z} A[m,k]*Beff[n,k]
// Beff = W_ih (+ W_hh for k<256). Tile 128x64, BK=32, 256 thr, 8x4 micro.
// LDS: As[32][132] (transposed) + Bs[32][68] = 25.6 KB.
// ---------------------------------------------------------------------------
__global__ __launch_bounds__(256) void gemm_gates_kernel(
    const float* __restrict__ A, const float* __restrict__ Bm,
    const float* __restrict__ Whh, float* __restrict__ Cpart, int Kper)
{
    __shared__ __align__(16) float As[32][132];
    __shared__ __align__(16) float Bs[32][68];
    const int tid = threadIdx.x;
    const int bm = blockIdx.y * 128, bn = blockIdx.x * 64;
    const int kbase = blockIdx.z * Kper;
    const int tx = tid & 15, ty = tid >> 4;      // n: 4*tx, m: 8*ty
    float acc[8][4] = {};

    for (int k0 = 0; k0 < Kper; k0 += 32) {
        const int kg = kbase + k0;               // block-uniform
        const bool addhh = (kg < DCH);
        #pragma unroll
        for (int i = 0; i < 4; ++i) {            // A tile: 128x32 = 1024 float4
            const int id = tid + i * 256;
            const int r = id >> 3, cc = id & 7;
            const float4 v = *(const float4*)(A + (size_t)(bm + r) * K2 + kg + 4 * cc);
            As[4*cc+0][r] = v.x; As[4*cc+1][r] = v.y; As[4*cc+2][r] = v.z; As[4*cc+3][r] = v.w;
        }
        #pragma unroll
        for (int i = 0; i < 2; ++i) {            // B tile: 64x32 = 512 float4
            const int id = tid + i * 256;
            const int r = id >> 3, cc = id & 7;
            float4 u = *(const float4*)(Bm + (size_t)(bn + r) * K2 + kg + 4 * cc);
            if (addhh) {
                const float4 h4 = *(const float4*)(Whh + (size_t)(bn + r) * DCH + kg + 4 * cc);
                u.x += h4.x; u.y += h4.y; u.z += h4.z; u.w += h4.w;
            }
            Bs[4*cc+0][r] = u.x; Bs[4*cc+1][r] = u.y; Bs[4*cc+2][r] = u.z; Bs[4*cc+3][r] = u.w;
        }
        __syncthreads();
        #pragma unroll
        for (int kk = 0; kk < 32; ++kk) {
            const float4 alo = *(const float4*)(&As[kk][8 * ty]);
            const float4 ahi = *(const float4*)(&As[kk][8 * ty + 4]);
            const float4 b4  = *(const float4*)(&Bs[kk][4 * tx]);
            acc[0][0] += alo.x * b4.x; acc[0][1] += alo.x * b4.y; acc[0][2] += alo.x * b4.z; acc[0][3] += alo.x * b4.w;
            acc[1][0] += alo.y * b4.x; acc[1][1] += alo.y * b4.y; acc[1][2] += alo.y * b4.z; acc[1][3] += alo.y * b4.w;
            acc[2][0] += alo.z * b4.x; acc[2][1] += alo.z * b4.y; acc[2][2] += alo.z * b4.z; acc[2][3] += alo.z * b4.w;
            acc[3][0] += alo.w * b4.x; acc[3][1] += alo.w * b4.y; acc[3][2] += alo.w * b4.z; acc[3][3] += alo.w * b4.w;
            acc[4][0] += ahi.x * b4.x; acc[4][1] += ahi.x * b4.y; acc[4][2] += ahi.x * b4.z; acc[4][3] += ahi.x * b4.w;
            acc[5][0] += ahi.y * b4.x; acc[5][1] += ahi.y * b4.y; acc[5][2] += ahi.y * b4.z; acc[5][3] += ahi.y * b4.w;
            acc[6][0] += ahi.z * b4.x; acc[6][1] += ahi.z * b4.y; acc[6][2] += ahi.z * b4.z; acc[6][3] += ahi.z * b4.w;
            acc[7][0] += ahi.w * b4.x; acc[7][1] += ahi.w * b4.y; acc[7][2] += ahi.w * b4.z; acc[7][3] += ahi.w * b4.w;
        }
        __syncthreads();
    }

    float* Cp = Cpart + (size_t)blockIdx.z * BSZ * G4;
    #pragma unroll
    for (int i = 0; i < 8; ++i) {
        float4 o;
        o.x = acc[i][0]; o.y = acc[i][1]; o.z = acc[i][2]; o.w = acc[i][3];
        *(float4*)(Cp + (size_t)(bm + 8 * ty + i) * G4 + bn + 4 * tx) = o;
    }
}

// ---------------------------------------------------------------------------
// Fused LSTM cell + online-softmax attention (+ output projection if LAST).
// One block per graph, 256 threads = 16 clusters of 16 lanes.
// smem layout (4640 floats): qs2[512] (h | r) , red_r[16][256] @512,
//   red_m[16] @4608, red_s[16] @4624. out_sm reuses red_r[0] area.
// ---------------------------------------------------------------------------
template<int FIRST, int LAST>
__global__ __launch_bounds__(256) void lstm_attn_kernel(
    const float* __restrict__ gpart,
    const float* __restrict__ b_ih, const float* __restrict__ b_hh,
    const float* __restrict__ node, const int* __restrict__ node_num,
    float* __restrict__ cbuf, float* __restrict__ hr,
    const float* __restrict__ Wo, const float* __restrict__ bo,
    float* __restrict__ outp)
{
    __shared__ __align__(16) float smem[4640];
    float* qs = smem;                                  // [512]: h | r
    float (*red_r)[DCH] = (float (*)[DCH])(smem + 512);
    float* red_m = smem + 4608;
    float* red_s = smem + 4624;

    const int b = blockIdx.x;
    const int t = threadIdx.x;

    // ---- LSTM cell (torch gate order i,f,g,o) ----
    float gv[4];
    #pragma unroll
    for (int q = 0; q < 4; ++q) {
        const int idx = q * DCH + t;
        float v = b_ih[idx] + b_hh[idx];
        if (!FIRST) {
            #pragma unroll
            for (int z = 0; z < KSD; ++z)
                v += gpart[(size_t)z * BSZ * G4 + (size_t)b * G4 + idx];
        }
        gv[q] = v;
    }
    const float c_old = FIRST ? 0.0f : cbuf[b * DCH + t];
    const float cn = sigf(gv[1]) * c_old + sigf(gv[0]) * tanhf(gv[2]);
    const float hn = sigf(gv[3]) * tanhf(cn);
    if (!LAST) {
        cbuf[b * DCH + t] = cn;
        hr[(size_t)b * K2 + t] = hn;
    }
    qs[t] = hn;
    __syncthreads();

    // ---- attention: 16-lane clusters, 2 nodes/cluster/iter, prefetch ----
    const int w = t >> 6, l = t & 63;
    const int p = l & 15;
    const int g = w * 4 + (l >> 4);
    const int cnt = node_num[b];
    const float* nb = node + (size_t)b * NPG * DCH;

    float4 qv[4];
    #pragma unroll
    for (int j = 0; j < 4; ++j) qv[j] = *(const float4*)(qs + j * 64 + p * 4);

    float m = -INFINITY, s = 0.0f;
    float4 racc[4] = {};
    const int nit = (cnt + 31) >> 5;

    float4 x0[4], x1[4];
    {
        const int n0 = 2 * g;
        #pragma unroll
        for (int j = 0; j < 4; ++j) {
            x0[j] = (n0     < cnt) ? *(const float4*)(nb + (size_t)n0 * DCH + j * 64 + p * 4)
                                   : make_float4(0.f, 0.f, 0.f, 0.f);
            x1[j] = (n0 + 1 < cnt) ? *(const float4*)(nb + (size_t)(n0 + 1) * DCH + j * 64 + p * 4)
                                   : make_float4(0.f, 0.f, 0.f, 0.f);
        }
    }

    for (int it = 0; it < nit; ++it) {
        float4 y0[4], y1[4];
        const int np = (it + 1) * 32 + 2 * g;
        #pragma unroll
        for (int j = 0; j < 4; ++j) {
            y0[j] = (np     < cnt) ? *(const float4*)(nb + (size_t)np * DCH + j * 64 + p * 4)
                                   : make_float4(0.f, 0.f, 0.f, 0.f);
            y1[j] = (np + 1 < cnt) ? *(const float4*)(nb + (size_t)(np + 1) * DCH + j * 64 + p * 4)
                                   : make_float4(0.f, 0.f, 0.f, 0.f);
        }
        float e0 = 0.f, e1 = 0.f;
        #pragma unroll
        for (int j = 0; j < 4; ++j) {
            e0 += x0[j].x * qv[j].x + x0[j].y * qv[j].y + x0[j].z * qv[j].z + x0[j].w * qv[j].w;
            e1 += x1[j].x * qv[j].x + x1[j].y * qv[j].y + x1[j].z * qv[j].z + x1[j].w * qv[j].w;
        }
        #pragma unroll
        for (int off = 1; off < 16; off <<= 1) {
            e0 += __shfl_xor(e0, off);
            e1 += __shfl_xor(e1, off);
        }
        const int n0 = it * 32 + 2 * g;
        if (n0     >= cnt) e0 = -INFINITY;
        if (n0 + 1 >= cnt) e1 = -INFINITY;
        const float mn = fmaxf(m, fmaxf(e0, e1));
        if (mn > -INFINITY) {
            const float sc = __expf(m - mn);
            const float w0 = __expf(e0 - mn);
            const float w1 = __expf(e1 - mn);
            s = s * sc + w0 + w1;
            #pragma unroll
            for (int j = 0; j < 4; ++j) {
                racc[j].x = racc[j].x * sc + w0 * x0[j].x + w1 * x1[j].x;
                racc[j].y = racc[j].y * sc + w0 * x0[j].y + w1 * x1[j].y;
                racc[j].z = racc[j].z * sc + w0 * x0[j].z + w1 * x1[j].z;
                racc[j].w = racc[j].w * sc + w0 * x0[j].w + w1 * x1[j].w;
            }
            m = mn;
        }
        #pragma unroll
        for (int j = 0; j < 4; ++j) { x0[j] = y0[j]; x1[j] = y1[j]; }
    }

    #pragma unroll
    for (int j = 0; j < 4; ++j)
        *(float4*)(&red_r[g][j * 64 + p * 4]) = racc[j];
    if (p == 0) { red_m[g] = m; red_s[g] = s; }
    __syncthreads();

    float M = -INFINITY;
    #pragma unroll
    for (int g2 = 0; g2 < 16; ++g2) M = fmaxf(M, red_m[g2]);
    float stot = 0.0f, rtot = 0.0f;
    #pragma unroll
    for (int g2 = 0; g2 < 16; ++g2) {
        const float sc = __expf(red_m[g2] - M);
        stot += sc * red_s[g2];
        rtot += sc * red_r[g2][t];
    }
    rtot = rtot / (stot + 1e-6f);

    if (!LAST) {
        hr[(size_t)b * K2 + DCH + t] = rtot;
        return;
    }

    // ---- fused output projection: out[b,o] = Wo[o,:]·[h|r] + bo[o] ----
    qs[256 + t] = rtot;                 // qs now holds full q_star[512]
    __syncthreads();

    float4 qv2[8];
    #pragma unroll
    for (int j = 0; j < 8; ++j) qv2[j] = *(const float4*)(qs + j * 64 + p * 4);
    float* out_sm = smem + 512;         // reuse red_r area (post-sync)

    #pragma unroll 2
    for (int v = 0; v < 8; ++v) {
        const int o0 = (2 * v) * 16 + g;
        const int o1 = o0 + 16;
        float e0 = 0.f, e1 = 0.f;
        #pragma unroll
        for (int j = 0; j < 8; ++j) {
            const float4 w0 = *(const float4*)(Wo + (size_t)o0 * K2 + j * 64 + p * 4);
            const float4 w1 = *(const float4*)(Wo + (size_t)o1 * K2 + j * 64 + p * 4);
            e0 += w0.x * qv2[j].x + w0.y * qv2[j].y + w0.z * qv2[j].z + w0.w * qv2[j].w;
            e1 += w1.x * qv2[j].x + w1.y * qv2[j].y + w1.z * qv2[j].z + w1.w * qv2[j].w;
        }
        #pragma unroll
        for (int off = 1; off < 16; off <<= 1) {
            e0 += __shfl_xor(e0, off);
            e1 += __shfl_xor(e1, off);
        }
        if (p == 0) {
            out_sm[o0] = e0 + bo[o0];
            out_sm[o1] = e1 + bo[o1];
        }
    }
    __syncthreads();
    outp[(size_t)b * DCH + t] = out_sm[t];
}

// ---------------------------------------------------------------------------
extern "C" void kernel_launch(void* const* d_in, const int* in_sizes, int n_in,
                              void* d_out, int out_size, void* d_ws, size_t ws_size,
                              hipStream_t stream)
{
    const float* node     = (const float*)d_in[0];
    const int*   node_num = (const int*)  d_in[1];
    const float* W_ih     = (const float*)d_in[2];
    const float* W_hh     = (const float*)d_in[3];
    const float* b_ih     = (const float*)d_in[4];
    const float* b_hh     = (const float*)d_in[5];
    const float* Wo       = (const float*)d_in[6];
    const float* bo       = (const float*)d_in[7];
    float* out = (float*)d_out;

    float* ws    = (float*)d_ws;
    float* cbuf  = ws;                        // 512*256
    float* hr    = cbuf + BSZ * DCH;          // 512*512
    float* gpart = hr + BSZ * K2;             // KSD*512*1024 (16 MB)

    // step 1: gates = biases only
    lstm_attn_kernel<1, 0><<<BSZ, 256, 0, stream>>>(
        gpart, b_ih, b_hh, node, node_num, cbuf, hr, Wo, bo, out);

    for (int s = 1; s < 4; ++s) {
        // gates partials: M=512,N=1024,K=512 ; tile 128x64, 16x4x8 = 512 blocks
        gemm_gates_kernel<<<dim3(G4 / 64, BSZ / 128, KSD), 256, 0, stream>>>(
            hr, W_ih, W_hh, gpart, K2 / KSD);
        if (s < 3) {
            lstm_attn_kernel<0, 0><<<BSZ, 256, 0, stream>>>(
                gpart, b_ih, b_hh, node, node_num, cbuf, hr, Wo, bo, out);
        } else {
            lstm_attn_kernel<0, 1><<<BSZ, 256, 0, stream>>>(
                gpart, b_ih, b_hh, node, node_num, cbuf, hr, Wo, bo, out);
        }
    }
}

// Round 8
// 120.759 us; speedup vs baseline: 1.9073x; 1.0696x over previous
//
#include <hip/hip_runtime.h>
#include <math.h>

#define DCH 256      // d_model
#define BSZ 512      // graphs
#define NPG 200      // nodes per graph
#define G4  1024     // 4*D
#define K2  512      // 2*D
#define KSD 8        // k-split for gates GEMM (grid 16x4x8 = 512 blocks)

__device__ __forceinline__ float sigf(float x) { return 1.0f / (1.0f + __expf(-x)); }

// ---- bf16 pack/unpack (RNE) ----
__device__ __forceinline__ unsigned pack2bf(float a, float b) {
    unsigned ua = __float_as_uint(a), ub = __float_as_uint(b);
    ua = (ua + 0x7FFFu + ((ua >> 16) & 1u)) >> 16;
    ub = (ub + 0x7FFFu + ((ub >> 16) & 1u)) & 0xFFFF0000u;
    return ua | ub;           // a -> low16, b -> high16
}
__device__ __forceinline__ float lo_bf(unsigned u) { return __uint_as_float(u << 16); }
__device__ __forceinline__ float hi_bf(unsigned u) { return __uint_as_float(u & 0xFFFF0000u); }

// ---------------------------------------------------------------------------
// Gates GEMM partial: Cpart[z][m,n] = sum_{k in slice z} A[m,k]*Beff[n,k]
// Beff = W_ih (+ W_hh for k<256). Tile 128x64, BK=32, 256 thr, 8x4 micro.
// ---------------------------------------------------------------------------
__global__ __launch_bounds__(256) void gemm_gates_kernel(
    const float* __restrict__ A, const float* __restrict__ Bm,
    const float* __restrict__ Whh, float* __restrict__ Cpart, int Kper)
{
    __shared__ __align__(16) float As[32][132];
    __shared__ __align__(16) float Bs[32][68];
    const int tid = threadIdx.x;
    const int bm = blockIdx.y * 128, bn = blockIdx.x * 64;
    const int kbase = blockIdx.z * Kper;
    const int tx = tid & 15, ty = tid >> 4;      // n: 4*tx, m: 8*ty
    float acc[8][4] = {};

    for (int k0 = 0; k0 < Kper; k0 += 32) {
        const int kg = kbase + k0;               // block-uniform
        const bool addhh = (kg < DCH);
        #pragma unroll
        for (int i = 0; i < 4; ++i) {            // A tile: 128x32 = 1024 float4
            const int id = tid + i * 256;
            const int r = id >> 3, cc = id & 7;
            const float4 v = *(const float4*)(A + (size_t)(bm + r) * K2 + kg + 4 * cc);
            As[4*cc+0][r] = v.x; As[4*cc+1][r] = v.y; As[4*cc+2][r] = v.z; As[4*cc+3][r] = v.w;
        }
        #pragma unroll
        for (int i = 0; i < 2; ++i) {            // B tile: 64x32 = 512 float4
            const int id = tid + i * 256;
            const int r = id >> 3, cc = id & 7;
            float4 u = *(const float4*)(Bm + (size_t)(bn + r) * K2 + kg + 4 * cc);
            if (addhh) {
                const float4 h4 = *(const float4*)(Whh + (size_t)(bn + r) * DCH + kg + 4 * cc);
                u.x += h4.x; u.y += h4.y; u.z += h4.z; u.w += h4.w;
            }
            Bs[4*cc+0][r] = u.x; Bs[4*cc+1][r] = u.y; Bs[4*cc+2][r] = u.z; Bs[4*cc+3][r] = u.w;
        }
        __syncthreads();
        #pragma unroll
        for (int kk = 0; kk < 32; ++kk) {
            const float4 alo = *(const float4*)(&As[kk][8 * ty]);
            const float4 ahi = *(const float4*)(&As[kk][8 * ty + 4]);
            const float4 b4  = *(const float4*)(&Bs[kk][4 * tx]);
            acc[0][0] += alo.x * b4.x; acc[0][1] += alo.x * b4.y; acc[0][2] += alo.x * b4.z; acc[0][3] += alo.x * b4.w;
            acc[1][0] += alo.y * b4.x; acc[1][1] += alo.y * b4.y; acc[1][2] += alo.y * b4.z; acc[1][3] += alo.y * b4.w;
            acc[2][0] += alo.z * b4.x; acc[2][1] += alo.z * b4.y; acc[2][2] += alo.z * b4.z; acc[2][3] += alo.z * b4.w;
            acc[3][0] += alo.w * b4.x; acc[3][1] += alo.w * b4.y; acc[3][2] += alo.w * b4.z; acc[3][3] += alo.w * b4.w;
            acc[4][0] += ahi.x * b4.x; acc[4][1] += ahi.x * b4.y; acc[4][2] += ahi.x * b4.z; acc[4][3] += ahi.x * b4.w;
            acc[5][0] += ahi.y * b4.x; acc[5][1] += ahi.y * b4.y; acc[5][2] += ahi.y * b4.z; acc[5][3] += ahi.y * b4.w;
            acc[6][0] += ahi.z * b4.x; acc[6][1] += ahi.z * b4.y; acc[6][2] += ahi.z * b4.z; acc[6][3] += ahi.z * b4.w;
            acc[7][0] += ahi.w * b4.x; acc[7][1] += ahi.w * b4.y; acc[7][2] += ahi.w * b4.z; acc[7][3] += ahi.w * b4.w;
        }
        __syncthreads();
    }

    float* Cp = Cpart + (size_t)blockIdx.z * BSZ * G4;
    #pragma unroll
    for (int i = 0; i < 8; ++i) {
        float4 o;
        o.x = acc[i][0]; o.y = acc[i][1]; o.z = acc[i][2]; o.w = acc[i][3];
        *(float4*)(Cp + (size_t)(bm + 8 * ty + i) * G4 + bn + 4 * tx) = o;
    }
}

// ---------------------------------------------------------------------------
// Fused LSTM cell + online-softmax attention (+ output projection if LAST).
// One block per graph, 256 threads = 16 clusters of 16 lanes.
// Lane p of a cluster owns dims {j*128 + p*8 .. +7} (8-dim granules).
// FIRST: reads fp32 node, also writes bf16 copy. !FIRST: reads bf16 copy.
// smem (4640 floats): qs[512] | red_r[16][256] @512 | red_m @4608 | red_s @4624
// ---------------------------------------------------------------------------
template<int FIRST, int LAST>
__global__ __launch_bounds__(256) void lstm_attn_kernel(
    const float* __restrict__ gpart,
    const float* __restrict__ b_ih, const float* __restrict__ b_hh,
    const float* __restrict__ node, uint4* __restrict__ nbf,
    const int* __restrict__ node_num,
    float* __restrict__ cbuf, float* __restrict__ hr,
    const float* __restrict__ Wo, const float* __restrict__ bo,
    float* __restrict__ outp)
{
    __shared__ __align__(16) float smem[4640];
    float* qs = smem;                                  // [512]: h | r
    float (*red_r)[DCH] = (float (*)[DCH])(smem + 512);
    float* red_m = smem + 4608;
    float* red_s = smem + 4624;

    const int b = blockIdx.x;
    const int t = threadIdx.x;

    // ---- LSTM cell (torch gate order i,f,g,o) ----
    float gv[4];
    #pragma unroll
    for (int q = 0; q < 4; ++q) {
        const int idx = q * DCH + t;
        float v = b_ih[idx] + b_hh[idx];
        if (!FIRST) {
            #pragma unroll
            for (int z = 0; z < KSD; ++z)
                v += gpart[(size_t)z * BSZ * G4 + (size_t)b * G4 + idx];
        }
        gv[q] = v;
    }
    const float c_old = FIRST ? 0.0f : cbuf[b * DCH + t];
    const float cn = sigf(gv[1]) * c_old + sigf(gv[0]) * tanhf(gv[2]);
    const float hn = sigf(gv[3]) * tanhf(cn);
    if (!LAST) {
        cbuf[b * DCH + t] = cn;
        hr[(size_t)b * K2 + t] = hn;
    }
    qs[t] = hn;
    __syncthreads();

    // ---- attention ----
    const int w = t >> 6, l = t & 63;
    const int p = l & 15;
    const int g = w * 4 + (l >> 4);
    const int cnt = node_num[b];
    const float* nb = node + (size_t)b * NPG * DCH;
    uint4* nbf_b = nbf + (size_t)b * NPG * 32;   // 32 uint4 per node

    float4 qv[4];
    #pragma unroll
    for (int j = 0; j < 2; ++j) {
        qv[j*2+0] = *(const float4*)(qs + j * 128 + p * 8);
        qv[j*2+1] = *(const float4*)(qs + j * 128 + p * 8 + 4);
    }

    auto ld_f32 = [&](int n, float4* x) {
        if (n < cnt) {
            #pragma unroll
            for (int j = 0; j < 2; ++j) {
                x[j*2+0] = *(const float4*)(nb + (size_t)n * DCH + j * 128 + p * 8);
                x[j*2+1] = *(const float4*)(nb + (size_t)n * DCH + j * 128 + p * 8 + 4);
            }
        } else {
            x[0] = x[1] = x[2] = x[3] = make_float4(0.f, 0.f, 0.f, 0.f);
        }
    };
    auto ld_bf = [&](int n, float4* x) {
        if (n < cnt) {
            #pragma unroll
            for (int j = 0; j < 2; ++j) {
                const uint4 u = nbf_b[(size_t)n * 32 + j * 16 + p];
                x[j*2+0] = make_float4(lo_bf(u.x), hi_bf(u.x), lo_bf(u.y), hi_bf(u.y));
                x[j*2+1] = make_float4(lo_bf(u.z), hi_bf(u.z), lo_bf(u.w), hi_bf(u.w));
            }
        } else {
            x[0] = x[1] = x[2] = x[3] = make_float4(0.f, 0.f, 0.f, 0.f);
        }
    };
    auto st_bf = [&](int n, const float4* x) {
        if (n < cnt) {
            #pragma unroll
            for (int j = 0; j < 2; ++j) {
                uint4 u;
                u.x = pack2bf(x[j*2+0].x, x[j*2+0].y);
                u.y = pack2bf(x[j*2+0].z, x[j*2+0].w);
                u.z = pack2bf(x[j*2+1].x, x[j*2+1].y);
                u.w = pack2bf(x[j*2+1].z, x[j*2+1].w);
                nbf_b[(size_t)n * 32 + j * 16 + p] = u;
            }
        }
    };

    float m = -INFINITY, s = 0.0f;
    float4 racc[4] = {};
    const int nit = (cnt + 31) >> 5;

    float4 x0[4], x1[4];
    if (FIRST) { ld_f32(2 * g, x0); ld_f32(2 * g + 1, x1); }
    else       { ld_bf (2 * g, x0); ld_bf (2 * g + 1, x1); }

    for (int it = 0; it < nit; ++it) {
        const int n0 = it * 32 + 2 * g;
        const int np = n0 + 32;
        float4 y0[4], y1[4];
        if (FIRST) { ld_f32(np, y0); ld_f32(np + 1, y1); }
        else       { ld_bf (np, y0); ld_bf (np + 1, y1); }
        if (FIRST) { st_bf(n0, x0); st_bf(n0 + 1, x1); }   // build bf16 cache

        float e0 = 0.f, e1 = 0.f;
        #pragma unroll
        for (int j = 0; j < 4; ++j) {
            e0 += x0[j].x * qv[j].x + x0[j].y * qv[j].y + x0[j].z * qv[j].z + x0[j].w * qv[j].w;
            e1 += x1[j].x * qv[j].x + x1[j].y * qv[j].y + x1[j].z * qv[j].z + x1[j].w * qv[j].w;
        }
        #pragma unroll
        for (int off = 1; off < 16; off <<= 1) {
            e0 += __shfl_xor(e0, off);
            e1 += __shfl_xor(e1, off);
        }
        if (n0     >= cnt) e0 = -INFINITY;
        if (n0 + 1 >= cnt) e1 = -INFINITY;
        const float mn = fmaxf(m, fmaxf(e0, e1));
        if (mn > -INFINITY) {
            const float sc = __expf(m - mn);
            const float w0 = __expf(e0 - mn);
            const float w1 = __expf(e1 - mn);
            s = s * sc + w0 + w1;
            #pragma unroll
            for (int j = 0; j < 4; ++j) {
                racc[j].x = racc[j].x * sc + w0 * x0[j].x + w1 * x1[j].x;
                racc[j].y = racc[j].y * sc + w0 * x0[j].y + w1 * x1[j].y;
                racc[j].z = racc[j].z * sc + w0 * x0[j].z + w1 * x1[j].z;
                racc[j].w = racc[j].w * sc + w0 * x0[j].w + w1 * x1[j].w;
            }
            m = mn;
        }
        #pragma unroll
        for (int j = 0; j < 4; ++j) { x0[j] = y0[j]; x1[j] = y1[j]; }
    }

    #pragma unroll
    for (int j = 0; j < 2; ++j) {
        *(float4*)(&red_r[g][j * 128 + p * 8])     = racc[j*2+0];
        *(float4*)(&red_r[g][j * 128 + p * 8 + 4]) = racc[j*2+1];
    }
    if (p == 0) { red_m[g] = m; red_s[g] = s; }
    __syncthreads();

    float M = -INFINITY;
    #pragma unroll
    for (int g2 = 0; g2 < 16; ++g2) M = fmaxf(M, red_m[g2]);
    float stot = 0.0f, rtot = 0.0f;
    #pragma unroll
    for (int g2 = 0; g2 < 16; ++g2) {
        const float sc = __expf(red_m[g2] - M);
        stot += sc * red_s[g2];
        rtot += sc * red_r[g2][t];
    }
    rtot = rtot / (stot + 1e-6f);

    if (!LAST) {
        hr[(size_t)b * K2 + DCH + t] = rtot;
        return;
    }

    // ---- fused output projection: out[b,o] = Wo[o,:]·[h|r] + bo[o] ----
    qs[256 + t] = rtot;                 // qs now holds full q_star[512]
    __syncthreads();

    float4 qv2[8];
    #pragma unroll
    for (int j = 0; j < 4; ++j) {
        qv2[j*2+0] = *(const float4*)(qs + j * 128 + p * 8);
        qv2[j*2+1] = *(const float4*)(qs + j * 128 + p * 8 + 4);
    }
    float* out_sm = smem + 512;         // reuse red_r area (post-sync)

    #pragma unroll 2
    for (int v = 0; v < 8; ++v) {
        const int o0 = (2 * v) * 16 + g;
        const int o1 = o0 + 16;
        float e0 = 0.f, e1 = 0.f;
        #pragma unroll
        for (int j = 0; j < 4; ++j) {
            const float4 wa0 = *(const float4*)(Wo + (size_t)o0 * K2 + j * 128 + p * 8);
            const float4 wa1 = *(const float4*)(Wo + (size_t)o0 * K2 + j * 128 + p * 8 + 4);
            const float4 wb0 = *(const float4*)(Wo + (size_t)o1 * K2 + j * 128 + p * 8);
            const float4 wb1 = *(const float4*)(Wo + (size_t)o1 * K2 + j * 128 + p * 8 + 4);
            e0 += wa0.x * qv2[j*2].x + wa0.y * qv2[j*2].y + wa0.z * qv2[j*2].z + wa0.w * qv2[j*2].w;
            e0 += wa1.x * qv2[j*2+1].x + wa1.y * qv2[j*2+1].y + wa1.z * qv2[j*2+1].z + wa1.w * qv2[j*2+1].w;
            e1 += wb0.x * qv2[j*2].x + wb0.y * qv2[j*2].y + wb0.z * qv2[j*2].z + wb0.w * qv2[j*2].w;
            e1 += wb1.x * qv2[j*2+1].x + wb1.y * qv2[j*2+1].y + wb1.z * qv2[j*2+1].z + wb1.w * qv2[j*2+1].w;
        }
        #pragma unroll
        for (int off = 1; off < 16; off <<= 1) {
            e0 += __shfl_xor(e0, off);
            e1 += __shfl_xor(e1, off);
        }
        if (p == 0) {
            out_sm[o0] = e0 + bo[o0];
            out_sm[o1] = e1 + bo[o1];
        }
    }
    __syncthreads();
    outp[(size_t)b * DCH + t] = out_sm[t];
}

// ---------------------------------------------------------------------------
extern "C" void kernel_launch(void* const* d_in, const int* in_sizes, int n_in,
                              void* d_out, int out_size, void* d_ws, size_t ws_size,
                              hipStream_t stream)
{
    const float* node     = (const float*)d_in[0];
    const int*   node_num = (const int*)  d_in[1];
    const float* W_ih     = (const float*)d_in[2];
    const float* W_hh     = (const float*)d_in[3];
    const float* b_ih     = (const float*)d_in[4];
    const float* b_hh     = (const float*)d_in[5];
    const float* Wo       = (const float*)d_in[6];
    const float* bo       = (const float*)d_in[7];
    float* out = (float*)d_out;

    float* ws    = (float*)d_ws;
    float* cbuf  = ws;                        // 512*256
    float* hr    = cbuf + BSZ * DCH;          // 512*512
    float* gpart = hr + BSZ * K2;             // KSD*512*1024 (16 MB)
    uint4* nbf   = (uint4*)(gpart + (size_t)KSD * BSZ * G4);  // 52.4 MB bf16 node

    // step 1: gates = biases only; also builds bf16 node cache
    lstm_attn_kernel<1, 0><<<BSZ, 256, 0, stream>>>(
        gpart, b_ih, b_hh, node, nbf, node_num, cbuf, hr, Wo, bo, out);

    for (int s = 1; s < 4; ++s) {
        gemm_gates_kernel<<<dim3(G4 / 64, BSZ / 128, KSD), 256, 0, stream>>>(
            hr, W_ih, W_hh, gpart, K2 / KSD);
        if (s < 3) {
            lstm_attn_kernel<0, 0><<<BSZ, 256, 0, stream>>>(
                gpart, b_ih, b_hh, node, nbf, node_num, cbuf, hr, Wo, bo, out);
        } else {
            lstm_attn_kernel<0, 1><<<BSZ, 256, 0, stream>>>(
                gpart, b_ih, b_hh, node, nbf, node_num, cbuf, hr, Wo, bo, out);
        }
    }
}

// Round 9
// 102.675 us; speedup vs baseline: 2.2432x; 1.1761x over previous
//
#include <hip/hip_runtime.h>
#include <math.h>

#define DCH 256      // d_model
#define BSZ 512      // graphs
#define NPG 200      // nodes per graph
#define G4  1024     // 4*D
#define K2  512      // 2*D
#define KSD 4        // k-split for gates GEMM (grid 8x8x4 = 256 blocks)

typedef __attribute__((ext_vector_type(8))) short short8v;  // 8 bf16 (4 VGPR)
typedef __attribute__((ext_vector_type(4))) float f32x4;

__device__ __forceinline__ float sigf(float x) { return 1.0f / (1.0f + __expf(-x)); }

// ---- bf16 pack/unpack (RNE) ----
__device__ __forceinline__ unsigned pack2bf(float a, float b) {
    unsigned ua = __float_as_uint(a), ub = __float_as_uint(b);
    ua = (ua + 0x7FFFu + ((ua >> 16) & 1u)) >> 16;
    ub = (ub + 0x7FFFu + ((ub >> 16) & 1u)) & 0xFFFF0000u;
    return ua | ub;           // a -> low16, b -> high16
}
__device__ __forceinline__ float lo_bf(unsigned u) { return __uint_as_float(u << 16); }
__device__ __forceinline__ float hi_bf(unsigned u) { return __uint_as_float(u & 0xFFFF0000u); }

// ---------------------------------------------------------------------------
// prep: Wcat[n][k] = bf16(W_ih[n,k] + (k<256 ? W_hh[n,k] : 0))  [1024x512]
//       WoBf[n][k] = bf16(Wo[n,k])                              [256x512]
// chunk = 8 bf16 = one uint4. 65536 + 16384 chunks = 320 blocks x 256 thr.
// ---------------------------------------------------------------------------
__global__ __launch_bounds__(256) void prep_kernel(
    const float* __restrict__ W_ih, const float* __restrict__ W_hh,
    const float* __restrict__ Wo,
    uint4* __restrict__ wcat, uint4* __restrict__ wobf)
{
    int idx = blockIdx.x * 256 + threadIdx.x;
    if (idx < 65536) {
        const int n = idx >> 6, k = (idx & 63) * 8;
        float v[8];
        *(float4*)(v)     = *(const float4*)(W_ih + (size_t)n * K2 + k);
        *(float4*)(v + 4) = *(const float4*)(W_ih + (size_t)n * K2 + k + 4);
        if (k < DCH) {
            float h[8];
            *(float4*)(h)     = *(const float4*)(W_hh + (size_t)n * DCH + k);
            *(float4*)(h + 4) = *(const float4*)(W_hh + (size_t)n * DCH + k + 4);
            #pragma unroll
            for (int i = 0; i < 8; ++i) v[i] += h[i];
        }
        uint4 u;
        u.x = pack2bf(v[0], v[1]); u.y = pack2bf(v[2], v[3]);
        u.z = pack2bf(v[4], v[5]); u.w = pack2bf(v[6], v[7]);
        wcat[idx] = u;
    } else {
        idx -= 65536;
        const int n = idx >> 6, k = (idx & 63) * 8;
        float v[8];
        *(float4*)(v)     = *(const float4*)(Wo + (size_t)n * K2 + k);
        *(float4*)(v + 4) = *(const float4*)(Wo + (size_t)n * K2 + k + 4);
        uint4 u;
        u.x = pack2bf(v[0], v[1]); u.y = pack2bf(v[2], v[3]);
        u.z = pack2bf(v[4], v[5]); u.w = pack2bf(v[6], v[7]);
        wobf[idx] = u;
    }
}

// ---------------------------------------------------------------------------
// MFMA gates GEMM partial: gpart[z][m][n] = sum_{k in slice z} qstar_bf[m,k]*Wcat[n,k]
// Block = 256 thr = 4 waves. Block tile M=64 x N=128; wave tile 64x32
// (4 M-subtiles x 2 N-subtiles of 16x16, K-steps of 32). Fragments loaded
// directly from global (A broadcast via L1; Wcat resident in L2).
// ---------------------------------------------------------------------------
__global__ __launch_bounds__(256) void gemm_gates_mfma(
    const unsigned short* __restrict__ hrbf,   // [BSZ][512] bf16 q_star
    const unsigned short* __restrict__ wcat,   // [1024][512] bf16
    float* __restrict__ gpart, int Kper)
{
    const int wid  = threadIdx.x >> 6;
    const int lane = threadIdx.x & 63;
    const int bm = blockIdx.y * 64;
    const int bn = blockIdx.x * 128 + wid * 32;
    const int kbase = blockIdx.z * Kper;
    const int rsel = lane & 15, kgrp = lane >> 4;

    f32x4 acc00 = {}, acc01 = {}, acc10 = {}, acc11 = {},
          acc20 = {}, acc21 = {}, acc30 = {}, acc31 = {};

    for (int k0 = 0; k0 < Kper; k0 += 32) {
        const int kk = kbase + k0 + kgrp * 8;
        short8v a0 = *(const short8v*)(hrbf + (size_t)(bm +  0 + rsel) * K2 + kk);
        short8v a1 = *(const short8v*)(hrbf + (size_t)(bm + 16 + rsel) * K2 + kk);
        short8v a2 = *(const short8v*)(hrbf + (size_t)(bm + 32 + rsel) * K2 + kk);
        short8v a3 = *(const short8v*)(hrbf + (size_t)(bm + 48 + rsel) * K2 + kk);
        short8v b0 = *(const short8v*)(wcat + (size_t)(bn +  0 + rsel) * K2 + kk);
        short8v b1 = *(const short8v*)(wcat + (size_t)(bn + 16 + rsel) * K2 + kk);
        acc00 = __builtin_amdgcn_mfma_f32_16x16x32_bf16(a0, b0, acc00, 0, 0, 0);
        acc01 = __builtin_amdgcn_mfma_f32_16x16x32_bf16(a0, b1, acc01, 0, 0, 0);
        acc10 = __builtin_amdgcn_mfma_f32_16x16x32_bf16(a1, b0, acc10, 0, 0, 0);
        acc11 = __builtin_amdgcn_mfma_f32_16x16x32_bf16(a1, b1, acc11, 0, 0, 0);
        acc20 = __builtin_amdgcn_mfma_f32_16x16x32_bf16(a2, b0, acc20, 0, 0, 0);
        acc21 = __builtin_amdgcn_mfma_f32_16x16x32_bf16(a2, b1, acc21, 0, 0, 0);
        acc30 = __builtin_amdgcn_mfma_f32_16x16x32_bf16(a3, b0, acc30, 0, 0, 0);
        acc31 = __builtin_amdgcn_mfma_f32_16x16x32_bf16(a3, b1, acc31, 0, 0, 0);
    }

    // C/D layout (m89-verified): col = lane&15, row = (lane>>4)*4 + reg
    float* Cp = gpart + (size_t)blockIdx.z * BSZ * G4;
    const int crow = kgrp * 4, ccol = rsel;
    const f32x4* accs[4][2] = { {&acc00, &acc01}, {&acc10, &acc11},
                                {&acc20, &acc21}, {&acc30, &acc31} };
    #pragma unroll
    for (int mi = 0; mi < 4; ++mi)
        #pragma unroll
        for (int ni = 0; ni < 2; ++ni)
            #pragma unroll
            for (int r = 0; r < 4; ++r)
                Cp[(size_t)(bm + mi * 16 + crow + r) * G4 + bn + ni * 16 + ccol] =
                    (*accs[mi][ni])[r];
}

// ---------------------------------------------------------------------------
// Fused LSTM cell + online-softmax attention (+ output projection if LAST).
// One block per graph, 256 threads = 16 clusters of 16 lanes.
// Lane p of a cluster owns dims {j*128 + p*8 .. +7}.
// FIRST: reads fp32 node, writes bf16 node cache. !FIRST: reads bf16 cache.
// Non-LAST: writes q_star as bf16 to hrbf. LAST: fused out-proj (bf16 Wo).
// smem (4640 floats): qs[512] | red_r[16][256] @512 | red_m @4608 | red_s @4624
// ---------------------------------------------------------------------------
template<int FIRST, int LAST>
__global__ __launch_bounds__(256) void lstm_attn_kernel(
    const float* __restrict__ gpart,
    const float* __restrict__ b_ih, const float* __restrict__ b_hh,
    const float* __restrict__ node, uint4* __restrict__ nbf,
    const int* __restrict__ node_num,
    float* __restrict__ cbuf, unsigned* __restrict__ hrbf,
    const uint4* __restrict__ wobf, const float* __restrict__ bo,
    float* __restrict__ outp)
{
    __shared__ __align__(16) float smem[4640];
    float* qs = smem;                                  // [512]: h | r
    float (*red_r)[DCH] = (float (*)[DCH])(smem + 512);
    float* red_m = smem + 4608;
    float* red_s = smem + 4624;

    const int b = blockIdx.x;
    const int t = threadIdx.x;

    // ---- LSTM cell (torch gate order i,f,g,o) ----
    float gv[4];
    #pragma unroll
    for (int q = 0; q < 4; ++q) {
        const int idx = q * DCH + t;
        float v = b_ih[idx] + b_hh[idx];
        if (!FIRST) {
            #pragma unroll
            for (int z = 0; z < KSD; ++z)
                v += gpart[(size_t)z * BSZ * G4 + (size_t)b * G4 + idx];
        }
        gv[q] = v;
    }
    const float c_old = FIRST ? 0.0f : cbuf[b * DCH + t];
    const float cn = sigf(gv[1]) * c_old + sigf(gv[0]) * tanhf(gv[2]);
    const float hn = sigf(gv[3]) * tanhf(cn);
    if (!LAST) cbuf[b * DCH + t] = cn;
    qs[t] = hn;
    __syncthreads();

    // ---- attention ----
    const int w = t >> 6, l = t & 63;
    const int p = l & 15;
    const int g = w * 4 + (l >> 4);
    const int cnt = node_num[b];
    const float* nb = node + (size_t)b * NPG * DCH;
    uint4* nbf_b = nbf + (size_t)b * NPG * 32;   // 32 uint4 per node

    float4 qv[4];
    #pragma unroll
    for (int j = 0; j < 2; ++j) {
        qv[j*2+0] = *(const float4*)(qs + j * 128 + p * 8);
        qv[j*2+1] = *(const float4*)(qs + j * 128 + p * 8 + 4);
    }

    auto ld_f32 = [&](int n, float4* x) {
        if (n < cnt) {
            #pragma unroll
            for (int j = 0; j < 2; ++j) {
                x[j*2+0] = *(const float4*)(nb + (size_t)n * DCH + j * 128 + p * 8);
                x[j*2+1] = *(const float4*)(nb + (size_t)n * DCH + j * 128 + p * 8 + 4);
            }
        } else {
            x[0] = x[1] = x[2] = x[3] = make_float4(0.f, 0.f, 0.f, 0.f);
        }
    };
    auto ld_bf = [&](int n, float4* x) {
        if (n < cnt) {
            #pragma unroll
            for (int j = 0; j < 2; ++j) {
                const uint4 u = nbf_b[(size_t)n * 32 + j * 16 + p];
                x[j*2+0] = make_float4(lo_bf(u.x), hi_bf(u.x), lo_bf(u.y), hi_bf(u.y));
                x[j*2+1] = make_float4(lo_bf(u.z), hi_bf(u.z), lo_bf(u.w), hi_bf(u.w));
            }
        } else {
            x[0] = x[1] = x[2] = x[3] = make_float4(0.f, 0.f, 0.f, 0.f);
        }
    };
    auto st_bf = [&](int n, const float4* x) {
        if (n < cnt) {
            #pragma unroll
            for (int j = 0; j < 2; ++j) {
                uint4 u;
                u.x = pack2bf(x[j*2+0].x, x[j*2+0].y);
                u.y = pack2bf(x[j*2+0].z, x[j*2+0].w);
                u.z = pack2bf(x[j*2+1].x, x[j*2+1].y);
                u.w = pack2bf(x[j*2+1].z, x[j*2+1].w);
                nbf_b[(size_t)n * 32 + j * 16 + p] = u;
            }
        }
    };

    float m = -INFINITY, s = 0.0f;
    float4 racc[4] = {};
    const int nit = (cnt + 31) >> 5;

    float4 x0[4], x1[4];
    if (FIRST) { ld_f32(2 * g, x0); ld_f32(2 * g + 1, x1); }
    else       { ld_bf (2 * g, x0); ld_bf (2 * g + 1, x1); }

    for (int it = 0; it < nit; ++it) {
        const int n0 = it * 32 + 2 * g;
        const int np = n0 + 32;
        float4 y0[4], y1[4];
        if (FIRST) { ld_f32(np, y0); ld_f32(np + 1, y1); }
        else       { ld_bf (np, y0); ld_bf (np + 1, y1); }
        if (FIRST) { st_bf(n0, x0); st_bf(n0 + 1, x1); }   // build bf16 cache

        float e0 = 0.f, e1 = 0.f;
        #pragma unroll
        for (int j = 0; j < 4; ++j) {
            e0 += x0[j].x * qv[j].x + x0[j].y * qv[j].y + x0[j].z * qv[j].z + x0[j].w * qv[j].w;
            e1 += x1[j].x * qv[j].x + x1[j].y * qv[j].y + x1[j].z * qv[j].z + x1[j].w * qv[j].w;
        }
        #pragma unroll
        for (int off = 1; off < 16; off <<= 1) {
            e0 += __shfl_xor(e0, off);
            e1 += __shfl_xor(e1, off);
        }
        if (n0     >= cnt) e0 = -INFINITY;
        if (n0 + 1 >= cnt) e1 = -INFINITY;
        const float mn = fmaxf(m, fmaxf(e0, e1));
        if (mn > -INFINITY) {
            const float sc = __expf(m - mn);
            const float w0 = __expf(e0 - mn);
            const float w1 = __expf(e1 - mn);
            s = s * sc + w0 + w1;
            #pragma unroll
            for (int j = 0; j < 4; ++j) {
                racc[j].x = racc[j].x * sc + w0 * x0[j].x + w1 * x1[j].x;
                racc[j].y = racc[j].y * sc + w0 * x0[j].y + w1 * x1[j].y;
                racc[j].z = racc[j].z * sc + w0 * x0[j].z + w1 * x1[j].z;
                racc[j].w = racc[j].w * sc + w0 * x0[j].w + w1 * x1[j].w;
            }
            m = mn;
        }
        #pragma unroll
        for (int j = 0; j < 4; ++j) { x0[j] = y0[j]; x1[j] = y1[j]; }
    }

    #pragma unroll
    for (int j = 0; j < 2; ++j) {
        *(float4*)(&red_r[g][j * 128 + p * 8])     = racc[j*2+0];
        *(float4*)(&red_r[g][j * 128 + p * 8 + 4]) = racc[j*2+1];
    }
    if (p == 0) { red_m[g] = m; red_s[g] = s; }
    __syncthreads();

    float M = -INFINITY;
    #pragma unroll
    for (int g2 = 0; g2 < 16; ++g2) M = fmaxf(M, red_m[g2]);
    float stot = 0.0f, rtot = 0.0f;
    #pragma unroll
    for (int g2 = 0; g2 < 16; ++g2) {
        const float sc = __expf(red_m[g2] - M);
        stot += sc * red_s[g2];
        rtot += sc * red_r[g2][t];
    }
    rtot = rtot / (stot + 1e-6f);

    // q_star = [h | r] into smem
    qs[256 + t] = rtot;
    __syncthreads();

    if (!LAST) {
        // pack q_star -> bf16 hrbf[b][512]
        hrbf[b * 256 + t] = pack2bf(qs[2 * t], qs[2 * t + 1]);
        return;
    }

    // ---- fused output projection: out[b,o] = Wo[o,:]·[h|r] + bo[o], Wo bf16 ----
    float4 qv2[8];
    #pragma unroll
    for (int j = 0; j < 4; ++j) {
        qv2[j*2+0] = *(const float4*)(qs + j * 128 + p * 8);
        qv2[j*2+1] = *(const float4*)(qs + j * 128 + p * 8 + 4);
    }
    float* out_sm = smem + 512;         // reuse red_r area (post-sync)

    #pragma unroll 2
    for (int v = 0; v < 8; ++v) {
        const int o0 = (2 * v) * 16 + g;
        const int o1 = o0 + 16;
        float e0 = 0.f, e1 = 0.f;
        #pragma unroll
        for (int j = 0; j < 4; ++j) {
            const uint4 ua = wobf[(size_t)o0 * 64 + j * 16 + p];
            const uint4 ub = wobf[(size_t)o1 * 64 + j * 16 + p];
            e0 += lo_bf(ua.x) * qv2[j*2].x + hi_bf(ua.x) * qv2[j*2].y
                + lo_bf(ua.y) * qv2[j*2].z + hi_bf(ua.y) * qv2[j*2].w
                + lo_bf(ua.z) * qv2[j*2+1].x + hi_bf(ua.z) * qv2[j*2+1].y
                + lo_bf(ua.w) * qv2[j*2+1].z + hi_bf(ua.w) * qv2[j*2+1].w;
            e1 += lo_bf(ub.x) * qv2[j*2].x + hi_bf(ub.x) * qv2[j*2].y
                + lo_bf(ub.y) * qv2[j*2].z + hi_bf(ub.y) * qv2[j*2].w
                + lo_bf(ub.z) * qv2[j*2+1].x + hi_bf(ub.z) * qv2[j*2+1].y
                + lo_bf(ub.w) * qv2[j*2+1].z + hi_bf(ub.w) * qv2[j*2+1].w;
        }
        #pragma unroll
        for (int off = 1; off < 16; off <<= 1) {
            e0 += __shfl_xor(e0, off);
            e1 += __shfl_xor(e1, off);
        }
        if (p == 0) {
            out_sm[o0] = e0 + bo[o0];
            out_sm[o1] = e1 + bo[o1];
        }
    }
    __syncthreads();
    outp[(size_t)b * DCH + t] = out_sm[t];
}

// ---------------------------------------------------------------------------
extern "C" void kernel_launch(void* const* d_in, const int* in_sizes, int n_in,
                              void* d_out, int out_size, void* d_ws, size_t ws_size,
                              hipStream_t stream)
{
    const float* node     = (const float*)d_in[0];
    const int*   node_num = (const int*)  d_in[1];
    const float* W_ih     = (const float*)d_in[2];
    const float* W_hh     = (const float*)d_in[3];
    const float* b_ih     = (const float*)d_in[4];
    const float* b_hh     = (const float*)d_in[5];
    const float* Wo       = (const float*)d_in[6];
    const float* bo       = (const float*)d_in[7];
    float* out = (float*)d_out;

    float* ws      = (float*)d_ws;
    float* cbuf    = ws;                                   // 512*256 f32
    unsigned* hrbf = (unsigned*)(cbuf + BSZ * DCH);        // 512*256 u32 (bf16 q_star)
    float* gpart   = (float*)(hrbf + BSZ * 256);           // KSD*512*1024 f32 (8 MB)
    uint4* wcat    = (uint4*)(gpart + (size_t)KSD * BSZ * G4);   // 1024*64 uint4 (1 MB)
    uint4* wobf    = wcat + 1024 * 64;                     // 256*64 uint4 (256 KB)
    uint4* nbf     = wobf + 256 * 64;                      // bf16 node cache (52.4 MB)

    prep_kernel<<<320, 256, 0, stream>>>(W_ih, W_hh, Wo, wcat, wobf);

    // step 1: gates = biases only; builds bf16 node cache
    lstm_attn_kernel<1, 0><<<BSZ, 256, 0, stream>>>(
        gpart, b_ih, b_hh, node, nbf, node_num, cbuf, hrbf, wobf, bo, out);

    for (int s = 1; s < 4; ++s) {
        gemm_gates_mfma<<<dim3(8, 8, KSD), 256, 0, stream>>>(
            (const unsigned short*)hrbf, (const unsigned short*)wcat, gpart, K2 / KSD);
        if (s < 3) {
            lstm_attn_kernel<0, 0><<<BSZ, 256, 0, stream>>>(
                gpart, b_ih, b_hh, node, nbf, node_num, cbuf, hrbf, wobf, bo, out);
        } else {
            lstm_attn_kernel<0, 1><<<BSZ, 256, 0, stream>>>(
                gpart, b_ih, b_hh, node, nbf, node_num, cbuf, hrbf, wobf, bo, out);
        }
    }
}

// Round 10
// 100.548 us; speedup vs baseline: 2.2906x; 1.0212x over previous
//
#include <hip/hip_runtime.h>
#include <math.h>

#define DCH 256      // d_model
#define BSZ 512      // graphs
#define NPG 200      // nodes per graph
#define G4  1024     // 4*D
#define K2  512      // 2*D
#define KSD 4        // k-split for gates GEMM (grid 8x8x4 = 256 blocks)

typedef __attribute__((ext_vector_type(8))) short short8v;  // 8 bf16 (4 VGPR)
typedef __attribute__((ext_vector_type(4))) float f32x4;

__device__ __forceinline__ float sigf(float x) { return 1.0f / (1.0f + __expf(-x)); }

// ---- bf16 pack/unpack (RNE) ----
__device__ __forceinline__ unsigned pack2bf(float a, float b) {
    unsigned ua = __float_as_uint(a), ub = __float_as_uint(b);
    ua = (ua + 0x7FFFu + ((ua >> 16) & 1u)) >> 16;
    ub = (ub + 0x7FFFu + ((ub >> 16) & 1u)) & 0xFFFF0000u;
    return ua | ub;           // a -> low16, b -> high16
}
__device__ __forceinline__ float lo_bf(unsigned u) { return __uint_as_float(u << 16); }
__device__ __forceinline__ float hi_bf(unsigned u) { return __uint_as_float(u & 0xFFFF0000u); }

// ---------------------------------------------------------------------------
// MFMA gates GEMM partial, operands SWAPPED (A = Wcat rows -> D rows = gates):
// gpart[z][m][n] = sum_{k in slice z} qstar_bf[m,k] * Wcat[n,k]
// Block = 4 waves; tile: gates 128 (x) x graphs 64 (y). Wave: 32 gates x 64
// graphs (2 n-sub x 4 m-sub of 16x16), K-steps of 32. C/D (m89-verified):
// col = lane&15 (B-side = graph), row = (lane>>4)*4 + reg (A-side = gate)
// -> each lane stores 8 float4 CONTIGUOUS in the gate dim.
// ---------------------------------------------------------------------------
__global__ __launch_bounds__(256) void gemm_gates_mfma(
    const unsigned short* __restrict__ hrbf,   // [BSZ][512] bf16 q_star
    const unsigned short* __restrict__ wcat,   // [1024][512] bf16
    float* __restrict__ gpart, int Kper)
{
    const int wid  = threadIdx.x >> 6;
    const int lane = threadIdx.x & 63;
    const int gx = blockIdx.x * 128 + wid * 32;   // gate base (A side)
    const int gm = blockIdx.y * 64;               // graph base (B side)
    const int kbase = blockIdx.z * Kper;
    const int rsel = lane & 15, kgrp = lane >> 4;

    f32x4 a0m0 = {}, a0m1 = {}, a0m2 = {}, a0m3 = {},
          a1m0 = {}, a1m1 = {}, a1m2 = {}, a1m3 = {};

    for (int k0 = 0; k0 < Kper; k0 += 32) {
        const int kk = kbase + k0 + kgrp * 8;
        short8v wa0 = *(const short8v*)(wcat + (size_t)(gx +  0 + rsel) * K2 + kk);
        short8v wa1 = *(const short8v*)(wcat + (size_t)(gx + 16 + rsel) * K2 + kk);
        short8v qb0 = *(const short8v*)(hrbf + (size_t)(gm +  0 + rsel) * K2 + kk);
        short8v qb1 = *(const short8v*)(hrbf + (size_t)(gm + 16 + rsel) * K2 + kk);
        short8v qb2 = *(const short8v*)(hrbf + (size_t)(gm + 32 + rsel) * K2 + kk);
        short8v qb3 = *(const short8v*)(hrbf + (size_t)(gm + 48 + rsel) * K2 + kk);
        a0m0 = __builtin_amdgcn_mfma_f32_16x16x32_bf16(wa0, qb0, a0m0, 0, 0, 0);
        a0m1 = __builtin_amdgcn_mfma_f32_16x16x32_bf16(wa0, qb1, a0m1, 0, 0, 0);
        a0m2 = __builtin_amdgcn_mfma_f32_16x16x32_bf16(wa0, qb2, a0m2, 0, 0, 0);
        a0m3 = __builtin_amdgcn_mfma_f32_16x16x32_bf16(wa0, qb3, a0m3, 0, 0, 0);
        a1m0 = __builtin_amdgcn_mfma_f32_16x16x32_bf16(wa1, qb0, a1m0, 0, 0, 0);
        a1m1 = __builtin_amdgcn_mfma_f32_16x16x32_bf16(wa1, qb1, a1m1, 0, 0, 0);
        a1m2 = __builtin_amdgcn_mfma_f32_16x16x32_bf16(wa1, qb2, a1m2, 0, 0, 0);
        a1m3 = __builtin_amdgcn_mfma_f32_16x16x32_bf16(wa1, qb3, a1m3, 0, 0, 0);
    }

    float* Cp = gpart + (size_t)blockIdx.z * BSZ * G4;
    const int gr = kgrp * 4;              // gate row sub-offset (4 contiguous)
    #define STORE_ACC(ni, mi, accv) \
        *(f32x4*)(Cp + (size_t)(gm + (mi)*16 + rsel) * G4 + gx + (ni)*16 + gr) = (accv);
    STORE_ACC(0, 0, a0m0) STORE_ACC(0, 1, a0m1) STORE_ACC(0, 2, a0m2) STORE_ACC(0, 3, a0m3)
    STORE_ACC(1, 0, a1m0) STORE_ACC(1, 1, a1m1) STORE_ACC(1, 2, a1m2) STORE_ACC(1, 3, a1m3)
    #undef STORE_ACC
}

// ---------------------------------------------------------------------------
// Fused LSTM cell + online-softmax attention (+ out-proj if LAST; + weight
// conversion if FIRST). One block per graph, 256 threads = 16 clusters x 16.
// Lane p of a cluster owns dims {j*128 + p*8 .. +7}. Depth-2 node prefetch.
// smem (4640 floats): qs[512] | red_r[16][256] @512 | red_m @4608 | red_s @4624
// ---------------------------------------------------------------------------
template<int FIRST, int LAST>
__global__ __launch_bounds__(256) void lstm_attn_kernel(
    const float* __restrict__ gpart,
    const float* __restrict__ b_ih, const float* __restrict__ b_hh,
    const float* __restrict__ node, uint4* __restrict__ nbf,
    const int* __restrict__ node_num,
    float* __restrict__ cbuf, unsigned* __restrict__ hrbf,
    const float* __restrict__ W_ih, const float* __restrict__ W_hh,
    const float* __restrict__ Wo,
    uint4* __restrict__ wcat, uint4* __restrict__ wobf,
    const float* __restrict__ bo, float* __restrict__ outp)
{
    __shared__ __align__(16) float smem[4640];
    float* qs = smem;                                  // [512]: h | r
    float (*red_r)[DCH] = (float (*)[DCH])(smem + 512);
    float* red_m = smem + 4608;
    float* red_s = smem + 4624;

    const int b = blockIdx.x;
    const int t = threadIdx.x;

    // ---- fused weight conversion (FIRST only): 160 chunks per block ----
    if (FIRST) {
        if (t < 160) {
            int idx = blockIdx.x * 160 + t;            // 0..81919
            if (idx < 65536) {                         // Wcat chunk
                const int n = idx >> 6, k = (idx & 63) * 8;
                float v[8];
                *(float4*)(v)     = *(const float4*)(W_ih + (size_t)n * K2 + k);
                *(float4*)(v + 4) = *(const float4*)(W_ih + (size_t)n * K2 + k + 4);
                if (k < DCH) {
                    float h[8];
                    *(float4*)(h)     = *(const float4*)(W_hh + (size_t)n * DCH + k);
                    *(float4*)(h + 4) = *(const float4*)(W_hh + (size_t)n * DCH + k + 4);
                    #pragma unroll
                    for (int i = 0; i < 8; ++i) v[i] += h[i];
                }
                uint4 u;
                u.x = pack2bf(v[0], v[1]); u.y = pack2bf(v[2], v[3]);
                u.z = pack2bf(v[4], v[5]); u.w = pack2bf(v[6], v[7]);
                wcat[idx] = u;
            } else {                                   // WoBf chunk
                const int i2 = idx - 65536;
                const int n = i2 >> 6, k = (i2 & 63) * 8;
                float v[8];
                *(float4*)(v)     = *(const float4*)(Wo + (size_t)n * K2 + k);
                *(float4*)(v + 4) = *(const float4*)(Wo + (size_t)n * K2 + k + 4);
                uint4 u;
                u.x = pack2bf(v[0], v[1]); u.y = pack2bf(v[2], v[3]);
                u.z = pack2bf(v[4], v[5]); u.w = pack2bf(v[6], v[7]);
                wobf[i2] = u;
            }
        }
    }

    // ---- LSTM cell (torch gate order i,f,g,o) ----
    float gv[4];
    #pragma unroll
    for (int q = 0; q < 4; ++q) {
        const int idx = q * DCH + t;
        float v = b_ih[idx] + b_hh[idx];
        if (!FIRST) {
            #pragma unroll
            for (int z = 0; z < KSD; ++z)
                v += gpart[(size_t)z * BSZ * G4 + (size_t)b * G4 + idx];
        }
        gv[q] = v;
    }
    const float c_old = FIRST ? 0.0f : cbuf[b * DCH + t];
    const float cn = sigf(gv[1]) * c_old + sigf(gv[0]) * tanhf(gv[2]);
    const float hn = sigf(gv[3]) * tanhf(cn);
    if (!LAST) cbuf[b * DCH + t] = cn;
    qs[t] = hn;
    __syncthreads();

    // ---- attention ----
    const int w = t >> 6, l = t & 63;
    const int p = l & 15;
    const int g = w * 4 + (l >> 4);
    const int cnt = node_num[b];
    const float* nb = node + (size_t)b * NPG * DCH;
    uint4* nbf_b = nbf + (size_t)b * NPG * 32;   // 32 uint4 per node

    float4 qv[4];
    #pragma unroll
    for (int j = 0; j < 2; ++j) {
        qv[j*2+0] = *(const float4*)(qs + j * 128 + p * 8);
        qv[j*2+1] = *(const float4*)(qs + j * 128 + p * 8 + 4);
    }

    auto ld = [&](int n, float4* x) {
        if (n < cnt) {
            if (FIRST) {
                #pragma unroll
                for (int j = 0; j < 2; ++j) {
                    x[j*2+0] = *(const float4*)(nb + (size_t)n * DCH + j * 128 + p * 8);
                    x[j*2+1] = *(const float4*)(nb + (size_t)n * DCH + j * 128 + p * 8 + 4);
                }
            } else {
                #pragma unroll
                for (int j = 0; j < 2; ++j) {
                    const uint4 u = nbf_b[(size_t)n * 32 + j * 16 + p];
                    x[j*2+0] = make_float4(lo_bf(u.x), hi_bf(u.x), lo_bf(u.y), hi_bf(u.y));
                    x[j*2+1] = make_float4(lo_bf(u.z), hi_bf(u.z), lo_bf(u.w), hi_bf(u.w));
                }
            }
        } else {
            x[0] = x[1] = x[2] = x[3] = make_float4(0.f, 0.f, 0.f, 0.f);
        }
    };
    auto st_bf = [&](int n, const float4* x) {
        if (n < cnt) {
            #pragma unroll
            for (int j = 0; j < 2; ++j) {
                uint4 u;
                u.x = pack2bf(x[j*2+0].x, x[j*2+0].y);
                u.y = pack2bf(x[j*2+0].z, x[j*2+0].w);
                u.z = pack2bf(x[j*2+1].x, x[j*2+1].y);
                u.w = pack2bf(x[j*2+1].z, x[j*2+1].w);
                nbf_b[(size_t)n * 32 + j * 16 + p] = u;
            }
        }
    };

    float m = -INFINITY, s = 0.0f;
    float4 racc[4] = {};
    const int nit = (cnt + 31) >> 5;

    // depth-2 pipeline: x = iter it, u = iter it+1, y = prefetch it+2
    float4 x0[4], x1[4], u0[4], u1[4];
    ld(2 * g, x0);      ld(2 * g + 1, x1);
    ld(32 + 2 * g, u0); ld(32 + 2 * g + 1, u1);

    for (int it = 0; it < nit; ++it) {
        const int n0 = it * 32 + 2 * g;
        float4 y0[4], y1[4];
        const int np = n0 + 64;                       // iter it+2
        ld(np, y0); ld(np + 1, y1);
        if (FIRST) { st_bf(n0, x0); st_bf(n0 + 1, x1); }   // build bf16 cache

        float e0 = 0.f, e1 = 0.f;
        #pragma unroll
        for (int j = 0; j < 4; ++j) {
            e0 += x0[j].x * qv[j].x + x0[j].y * qv[j].y + x0[j].z * qv[j].z + x0[j].w * qv[j].w;
            e1 += x1[j].x * qv[j].x + x1[j].y * qv[j].y + x1[j].z * qv[j].z + x1[j].w * qv[j].w;
        }
        #pragma unroll
        for (int off = 1; off < 16; off <<= 1) {
            e0 += __shfl_xor(e0, off);
            e1 += __shfl_xor(e1, off);
        }
        if (n0     >= cnt) e0 = -INFINITY;
        if (n0 + 1 >= cnt) e1 = -INFINITY;
        const float mn = fmaxf(m, fmaxf(e0, e1));
        if (mn > -INFINITY) {
            const float sc = __expf(m - mn);
            const float w0 = __expf(e0 - mn);
            const float w1 = __expf(e1 - mn);
            s = s * sc + w0 + w1;
            #pragma unroll
            for (int j = 0; j < 4; ++j) {
                racc[j].x = racc[j].x * sc + w0 * x0[j].x + w1 * x1[j].x;
                racc[j].y = racc[j].y * sc + w0 * x0[j].y + w1 * x1[j].y;
                racc[j].z = racc[j].z * sc + w0 * x0[j].z + w1 * x1[j].z;
                racc[j].w = racc[j].w * sc + w0 * x0[j].w + w1 * x1[j].w;
            }
            m = mn;
        }
        #pragma unroll
        for (int j = 0; j < 4; ++j) {
            x0[j] = u0[j]; x1[j] = u1[j];
            u0[j] = y0[j]; u1[j] = y1[j];
        }
    }

    #pragma unroll
    for (int j = 0; j < 2; ++j) {
        *(float4*)(&red_r[g][j * 128 + p * 8])     = racc[j*2+0];
        *(float4*)(&red_r[g][j * 128 + p * 8 + 4]) = racc[j*2+1];
    }
    if (p == 0) { red_m[g] = m; red_s[g] = s; }
    __syncthreads();

    float M = -INFINITY;
    #pragma unroll
    for (int g2 = 0; g2 < 16; ++g2) M = fmaxf(M, red_m[g2]);
    float stot = 0.0f, rtot = 0.0f;
    #pragma unroll
    for (int g2 = 0; g2 < 16; ++g2) {
        const float sc = __expf(red_m[g2] - M);
        stot += sc * red_s[g2];
        rtot += sc * red_r[g2][t];
    }
    rtot = rtot / (stot + 1e-6f);

    // q_star = [h | r] into smem
    qs[256 + t] = rtot;
    __syncthreads();

    if (!LAST) {
        // pack q_star -> bf16 hrbf[b][512]
        hrbf[b * 256 + t] = pack2bf(qs[2 * t], qs[2 * t + 1]);
        return;
    }

    // ---- fused output projection: out[b,o] = Wo[o,:]·[h|r] + bo[o], Wo bf16 ----
    float4 qv2[8];
    #pragma unroll
    for (int j = 0; j < 4; ++j) {
        qv2[j*2+0] = *(const float4*)(qs + j * 128 + p * 8);
        qv2[j*2+1] = *(const float4*)(qs + j * 128 + p * 8 + 4);
    }
    float* out_sm = smem + 512;         // reuse red_r area (post-sync)

    #pragma unroll 2
    for (int v = 0; v < 8; ++v) {
        const int o0 = (2 * v) * 16 + g;
        const int o1 = o0 + 16;
        float e0 = 0.f, e1 = 0.f;
        #pragma unroll
        for (int j = 0; j < 4; ++j) {
            const uint4 ua = wobf[(size_t)o0 * 64 + j * 16 + p];
            const uint4 ub = wobf[(size_t)o1 * 64 + j * 16 + p];
            e0 += lo_bf(ua.x) * qv2[j*2].x + hi_bf(ua.x) * qv2[j*2].y
                + lo_bf(ua.y) * qv2[j*2].z + hi_bf(ua.y) * qv2[j*2].w
                + lo_bf(ua.z) * qv2[j*2+1].x + hi_bf(ua.z) * qv2[j*2+1].y
                + lo_bf(ua.w) * qv2[j*2+1].z + hi_bf(ua.w) * qv2[j*2+1].w;
            e1 += lo_bf(ub.x) * qv2[j*2].x + hi_bf(ub.x) * qv2[j*2].y
                + lo_bf(ub.y) * qv2[j*2].z + hi_bf(ub.y) * qv2[j*2].w
                + lo_bf(ub.z) * qv2[j*2+1].x + hi_bf(ub.z) * qv2[j*2+1].y
                + lo_bf(ub.w) * qv2[j*2+1].z + hi_bf(ub.w) * qv2[j*2+1].w;
        }
        #pragma unroll
        for (int off = 1; off < 16; off <<= 1) {
            e0 += __shfl_xor(e0, off);
            e1 += __shfl_xor(e1, off);
        }
        if (p == 0) {
            out_sm[o0] = e0 + bo[o0];
            out_sm[o1] = e1 + bo[o1];
        }
    }
    __syncthreads();
    outp[(size_t)b * DCH + t] = out_sm[t];
}

// ---------------------------------------------------------------------------
extern "C" void kernel_launch(void* const* d_in, const int* in_sizes, int n_in,
                              void* d_out, int out_size, void* d_ws, size_t ws_size,
                              hipStream_t stream)
{
    const float* node     = (const float*)d_in[0];
    const int*   node_num = (const int*)  d_in[1];
    const float* W_ih     = (const float*)d_in[2];
    const float* W_hh     = (const float*)d_in[3];
    const float* b_ih     = (const float*)d_in[4];
    const float* b_hh     = (const float*)d_in[5];
    const float* Wo       = (const float*)d_in[6];
    const float* bo       = (const float*)d_in[7];
    float* out = (float*)d_out;

    float* ws      = (float*)d_ws;
    float* cbuf    = ws;                                   // 512*256 f32
    unsigned* hrbf = (unsigned*)(cbuf + BSZ * DCH);        // 512*256 u32 (bf16 q_star)
    float* gpart   = (float*)(hrbf + BSZ * 256);           // KSD*512*1024 f32 (8 MB)
    uint4* wcat    = (uint4*)(gpart + (size_t)KSD * BSZ * G4);   // 1024*64 uint4 (1 MB)
    uint4* wobf    = wcat + 1024 * 64;                     // 256*64 uint4 (256 KB)
    uint4* nbf     = wobf + 256 * 64;                      // bf16 node cache (52.4 MB)

    // step 1: gates = biases only; builds bf16 node cache + bf16 weights
    lstm_attn_kernel<1, 0><<<BSZ, 256, 0, stream>>>(
        gpart, b_ih, b_hh, node, nbf, node_num, cbuf, hrbf,
        W_ih, W_hh, Wo, wcat, wobf, bo, out);

    for (int s = 1; s < 4; ++s) {
        gemm_gates_mfma<<<dim3(8, 8, KSD), 256, 0, stream>>>(
            (const unsigned short*)hrbf, (const unsigned short*)wcat, gpart, K2 / KSD);
        if (s < 3) {
            lstm_attn_kernel<0, 0><<<BSZ, 256, 0, stream>>>(
                gpart, b_ih, b_hh, node, nbf, node_num, cbuf, hrbf,
                W_ih, W_hh, Wo, wcat, wobf, bo, out);
        } else {
            lstm_attn_kernel<0, 1><<<BSZ, 256, 0, stream>>>(
                gpart, b_ih, b_hh, node, nbf, node_num, cbuf, hrbf,
                W_ih, W_hh, Wo, wcat, wobf, bo, out);
        }
    }
}